// Round 2
// baseline (590.263 us; speedup 1.0000x reference)
//
#include <hip/hip_runtime.h>
#include <hip/hip_bf16.h>
#include <math.h>
#include <cstdint>

typedef unsigned long long u64;
typedef unsigned int u32;
typedef _Float16 half8 __attribute__((ext_vector_type(8)));
typedef float floatx4 __attribute__((ext_vector_type(4)));

// ---------------------------------------------------------------------------
// Sizes
// ---------------------------------------------------------------------------
#define NANCH 36864        // 4096*9
#define SEG 65536          // padded per-image sort segment
#define N_PRE 6000
#define N_POST 300
#define NW 96              // mask words per row (6144 bits)
#define NPADC 6144         // padded candidate count

// output float offsets
#define O0 0               // rpn_locs  2*36864*4 = 294912
#define O1 294912          // rpn_scores 2*36864*2 = 147456
#define O2 442368          // rois 2*300*4 = 2400
#define O3 444768          // roi_indices 600
#define O4 445368          // anchor 147456
#define O5 592824          // vmask 600

// workspace float offsets
#define WS_XHI   0                        // xhi f16 [2][4096][512] (2,097,152 f)
#define WS_XLO   2097152
#define WS_WHI   4194304                  // whi f16 [9][512][512] (1,179,648 f)
#define WS_WLO   5373952
#define WS_WSLT  6553600                  // 32768
#define WS_WSLB  6586368                  // 64
#define WS_H     6586432                  // hbuf f32 [2][4096][512] = 4,194,304 f
#define WS_GUARD 10780736                 // 64 floats of zeros (OOB target)
// overlays into dead XHI region (used only after conv completes):
#define WS_FG    0                        // 73728
#define WS_ROI   73728                    // 294912 (16B aligned)
#define WS_KEYS  368640                   // 131072 u64 = 262144 f
#define WS_SBOX  630784                   // 2*6144 float4 = 49152 f
#define WS_ALIVE 679936                   // 2*96 u64 = 384 f
// overlay into dead WHI+WLO region (after conv): FULL suppression matrix
#define WS_MASK  4194304                  // 2*6144*96 u64 = 9,437,184 B (exact fit)

#define HSCALE 9.5367431640625e-07f       // 2^-20

// ---------------------------------------------------------------------------
__device__ __forceinline__ void gl_lds16(const void* g, void* l) {
  __builtin_amdgcn_global_load_lds(
      (const __attribute__((address_space(1))) u32*)g,
      (__attribute__((address_space(3))) u32*)l, 16, 0, 0);
}

__device__ __forceinline__ u64 bcast64(u64 v, int src) {
  u32 lo = (u32)__shfl((int)(v & 0xFFFFFFFFull), src);
  u32 hi = (u32)__shfl((int)(v >> 32), src);
  return ((u64)hi << 32) | lo;
}

// ---------------------------------------------------------------------------
// 0. fused prep: zero hbuf+guard | xcvt | wcvt | head-weight pack.
// Linear grid: [0,4097) zero, [4097,5121) xcvt, [5121,5697) wcvt,
// [5697,5826) prep_small.
// ---------------------------------------------------------------------------
__global__ __launch_bounds__(256) void prep_all(
    const float* __restrict__ x, const float* __restrict__ w,
    const float* __restrict__ lw, const float* __restrict__ sw,
    const float* __restrict__ lb, const float* __restrict__ sb,
    float4* __restrict__ h, float4* __restrict__ guard,
    _Float16* __restrict__ xhi, _Float16* __restrict__ xlo,
    _Float16* __restrict__ whi, _Float16* __restrict__ wlo,
    float* __restrict__ wslt, float* __restrict__ wslb) {
  __shared__ float s[64 * 65];
  const int b = blockIdx.x, tid = threadIdx.x;
  if (b < 4097) {
    int idx = b * 256 + tid;
    if (idx < 1048576) h[idx] = make_float4(0.f, 0.f, 0.f, 0.f);
    else if (idx < 1048576 + 16) guard[idx - 1048576] = make_float4(0.f, 0.f, 0.f, 0.f);
    return;
  }
  if (b < 5121) {  // xcvt: [n][c][pix] f32 -> [n][pix][c] f16 hi/lo x1024
    int l = b - 4097;
    int pt = l & 63, cg = (l >> 6) & 7, n = l >> 9;
    const int c0 = cg << 6, p0 = pt << 6;
#pragma unroll
    for (int kk = 0; kk < 16; ++kk) {
      int e = tid + (kk << 8);
      int ci = e >> 6, pi = e & 63;
      s[ci * 65 + pi] = x[(((size_t)(n * 512 + c0 + ci)) << 12) + p0 + pi];
    }
    __syncthreads();
#pragma unroll
    for (int kk = 0; kk < 16; ++kk) {
      int e = tid + (kk << 8);
      int ci = e & 63, pi = e >> 6;
      float sv = s[ci * 65 + pi] * 1024.f;
      _Float16 hi = (_Float16)sv;
      _Float16 lo = (_Float16)(sv - (float)hi);
      size_t off = (((size_t)(n << 12) + p0 + pi) << 9) + c0 + ci;
      xhi[off] = hi;
      xlo[off] = lo;
    }
    return;
  }
  if (b < 5697) {  // wcvt: [o][c][3][3] -> [t][o][c] f16 hi/lo x1024
    int l = b - 5121;
    int ct = l & 7, ot = (l >> 3) & 7, t = l >> 6;
    const int c0 = ct << 6, o0 = ot << 6;
#pragma unroll
    for (int kk = 0; kk < 16; ++kk) {
      int e = tid + (kk << 8);
      int ci = e & 63, oi = e >> 6;
      float sv = w[(size_t)(o0 + oi) * 4608 + (c0 + ci) * 9 + t] * 1024.f;
      _Float16 hi = (_Float16)sv;
      _Float16 lo = (_Float16)(sv - (float)hi);
      size_t off = ((size_t)((t << 9) + o0 + oi) << 9) + c0 + ci;
      whi[off] = hi;
      wlo[off] = lo;
    }
    return;
  }
  {  // prep_small
    int e = (b - 5697) * 256 + tid;
    if (e < 32768) {
      int c = e >> 6, o = e & 63;
      float v = 0.f;
      if (o < 36) v = lw[o * 512 + c];
      else if (o < 54) v = sw[(o - 36) * 512 + c];
      wslt[e] = v;
    } else if (e < 32832) {
      int o = e - 32768;
      float v = 0.f;
      if (o < 36) v = lb[o];
      else if (o < 54) v = sb[o - 36];
      wslb[o] = v;
    }
  }
}

// ---------------------------------------------------------------------------
// 1. MFMA implicit-GEMM 3x3 conv.
// R6: pass-split. The fp16x2 split (hh + hl + lh) runs as THREE independent
// blocks (blockIdx.z), and the old kq channel-split is merged into the s
// loop. Grid 64x4x3 = 768 = exactly 3 blocks/CU (was 512 = 2/CU): 12
// waves/CU interleave staging stalls across independent blocks. LDS halves
// to 25.6 KB (one A array + one B array). R1's intra-block pipelining
// regressed (129 us): with 2 blocks/CU the problem was occupancy, not the
// schedule — per m114, cross-block overlap IS the pipeline.
// ---------------------------------------------------------------------------
__global__ __launch_bounds__(256) void conv_mfma(
    const _Float16* __restrict__ xhi, const _Float16* __restrict__ xlo,
    const _Float16* __restrict__ whi, const _Float16* __restrict__ wlo,
    const float* __restrict__ guard, float* __restrict__ hout) {
  __shared__ _Float16 aS[4 * 68 * 32];
  __shared__ _Float16 bS[128 * 32];
  const int tid = threadIdx.x;
  const int lane = tid & 63, w = tid >> 6;
  const int ptile = blockIdx.x;
  const int og = blockIdx.y;
  const int pass = blockIdx.z;           // 0: xhi*whi, 1: xhi*wlo, 2: xlo*whi
  const _Float16* __restrict__ Asrc = (pass == 2) ? xlo : xhi;
  const _Float16* __restrict__ Bsrc = (pass == 1) ? wlo : whi;
  const int n = ptile >> 5;
  const int y0 = (ptile & 31) << 1;
  const int o0 = og << 7;
  const int l15 = lane & 15, l16 = lane >> 4;
  const int ry = w >> 1;
  const int wo = (w & 1) << 6;

  floatx4 acc[4][4];
#pragma unroll
  for (int a = 0; a < 4; ++a)
#pragma unroll
    for (int b = 0; b < 4; ++b) acc[a][b] = (floatx4)0.f;

  for (int s = 0; s < 16; ++s) {
    const int c0 = s << 5;
    __syncthreads();
    for (int i = w; i < 17; i += 4) {
      int chunk = (i << 6) + lane;
      int p = chunk >> 2, q = chunk & 3;
      int r = p / 68, xs = p - r * 68;
      int y = y0 - 1 + r, xg = xs - 1;
      bool ok = ((unsigned)y < 64u) && ((unsigned)xg < 64u);
      size_t off = (((size_t)(n << 12) + (y << 6) + xg) << 9) + c0 + (q << 3);
      const void* ga = ok ? (const void*)(Asrc + off) : (const void*)guard;
      gl_lds16(ga, (char*)aS + (i << 10));
    }
    for (int tt = 0; tt < 9; ++tt) {
      if (tt > 0) __syncthreads();
      for (int i = w; i < 8; i += 4) {
        int chunk = (i << 6) + lane;
        int row = chunk >> 2, q = chunk & 3;
        size_t off = ((size_t)((tt << 9) + o0 + row) << 9) + c0 + (q << 3);
        gl_lds16((const void*)(Bsrc + off), (char*)bS + (i << 10));
      }
      __syncthreads();

      const int dy = tt / 3, dx = tt - 3 * dy;
      half8 av[4], bv[4];
#pragma unroll
      for (int im = 0; im < 4; ++im) {
        int xp = (im << 4) + l15;
        int p = (ry + dy) * 68 + xp + dx;
        av[im] = *(const half8*)&aS[(p << 5) + (l16 << 3)];
      }
#pragma unroll
      for (int in = 0; in < 4; ++in) {
        int orow = wo + (in << 4) + l15;
        bv[in] = *(const half8*)&bS[(orow << 5) + (l16 << 3)];
      }
#pragma unroll
      for (int im = 0; im < 4; ++im)
#pragma unroll
        for (int in = 0; in < 4; ++in)
          acc[im][in] = __builtin_amdgcn_mfma_f32_16x16x32_f16(
              av[im], bv[in], acc[im][in], 0, 0, 0);
    }
  }

#pragma unroll
  for (int im = 0; im < 4; ++im)
#pragma unroll
    for (int in = 0; in < 4; ++in) {
      int o = o0 + wo + (in << 4) + l15;
#pragma unroll
      for (int reg = 0; reg < 4; ++reg) {
        int m_local = (ry << 6) + (im << 4) + (l16 << 2) + reg;
        size_t off = (((size_t)(n << 12) + (y0 << 6) + m_local) << 9) + o;
        atomicAdd(&hout[off], acc[im][in][reg]);
      }
    }
}

// ---------------------------------------------------------------------------
// 2. 1x1 heads + softmax. grid (64 y, 2 n), block 256.
// ---------------------------------------------------------------------------
__global__ __launch_bounds__(256) void head_kernel(
    const float* __restrict__ hbuf, const float* __restrict__ cb,
    const float* __restrict__ wslt, const float* __restrict__ wslb,
    float* __restrict__ out, float* __restrict__ fgbuf) {
  const int y = blockIdx.x, n = blockIdx.y;
  __shared__ float sH[16 * 65];
  __shared__ float sWt[1024];
  __shared__ float sOut[64 * 65];
  const int tid = threadIdx.x;
  const int x = tid & 63, og = tid >> 6;

  float acc[16];
#pragma unroll
  for (int j = 0; j < 16; ++j) acc[j] = 0.f;

  const float* hb = hbuf + (((size_t)(n << 12) + (y << 6)) << 9);

  for (int c0 = 0; c0 < 512; c0 += 16) {
    __syncthreads();
#pragma unroll
    for (int p = 0; p < 4; ++p) {
      int e = tid + (p << 8);
      {
        int cc = e & 15, xx = e >> 4;
        float raw = hb[((size_t)xx << 9) + c0 + cc];
        sH[cc * 65 + xx] = fmaxf(raw * HSCALE + cb[c0 + cc], 0.f);
      }
      {
        int cc = e >> 6, xx = e & 63;
        sWt[e] = wslt[((c0 + cc) << 6) + xx];
      }
    }
    __syncthreads();
#pragma unroll
    for (int cc = 0; cc < 16; ++cc) {
      float hv = sH[cc * 65 + x];
      const float4* wp = (const float4*)&sWt[(cc << 6) + (og << 4)];
      float4 w0 = wp[0], w1 = wp[1], w2 = wp[2], w3 = wp[3];
      acc[0]  = fmaf(hv, w0.x, acc[0]);  acc[1]  = fmaf(hv, w0.y, acc[1]);
      acc[2]  = fmaf(hv, w0.z, acc[2]);  acc[3]  = fmaf(hv, w0.w, acc[3]);
      acc[4]  = fmaf(hv, w1.x, acc[4]);  acc[5]  = fmaf(hv, w1.y, acc[5]);
      acc[6]  = fmaf(hv, w1.z, acc[6]);  acc[7]  = fmaf(hv, w1.w, acc[7]);
      acc[8]  = fmaf(hv, w2.x, acc[8]);  acc[9]  = fmaf(hv, w2.y, acc[9]);
      acc[10] = fmaf(hv, w2.z, acc[10]); acc[11] = fmaf(hv, w2.w, acc[11]);
      acc[12] = fmaf(hv, w3.x, acc[12]); acc[13] = fmaf(hv, w3.y, acc[13]);
      acc[14] = fmaf(hv, w3.z, acc[14]); acc[15] = fmaf(hv, w3.w, acc[15]);
    }
  }
  __syncthreads();
#pragma unroll
  for (int j = 0; j < 16; ++j) {
    int o = (og << 4) + j;
    sOut[o * 65 + x] = acc[j] + wslb[o];
  }
  __syncthreads();

  const int p0 = (n << 12) + (y << 6);
  float* locs = out + O0 + (size_t)p0 * 36;
  for (int e = tid; e < 2304; e += 256) {
    int xx = e / 36, o = e - xx * 36;
    locs[e] = sOut[o * 65 + xx];
  }
  float* scrs = out + O1 + (size_t)p0 * 18;
  for (int e = tid; e < 1152; e += 256) {
    int xx = e / 18, ss = e - xx * 18;
    scrs[e] = sOut[(36 + ss) * 65 + xx];
  }
  float* fg = fgbuf + n * NANCH + (y << 6) * 9;
  for (int e = tid; e < 576; e += 256) {
    int xx = e / 9, a = e - xx * 9;
    float s0 = sOut[(36 + 2 * a) * 65 + xx];
    float s1 = sOut[(36 + 2 * a + 1) * 65 + xx];
    fg[e] = 1.0f / (1.0f + expf(s0 - s1));
  }
}

// ---------------------------------------------------------------------------
// 3. anchors + decode + clip + min-size + sort keys (+ init out regions).
// ---------------------------------------------------------------------------
__global__ __launch_bounds__(256) void decode_kernel(
    const float* __restrict__ out0, const float* __restrict__ fgbuf,
    float4* __restrict__ roibuf, u64* __restrict__ keys,
    float* __restrict__ anchor_out, float* __restrict__ out,
    const int* __restrict__ imgh_p, const int* __restrict__ imgw_p) {
  int gid = blockIdx.x * 256 + threadIdx.x;   // < 131072
  if (gid < 3600) {
    if (gid < 2400) out[O2 + gid] = 0.f;
    else if (gid < 3000) out[O3 + (gid - 2400)] = (float)((gid - 2400) / 300);
    else out[O5 + (gid - 3000)] = 0.f;
  }
  int n = gid >> 16, k = gid & (SEG - 1);
  if (k >= NANCH) { keys[gid] = ~0ull; return; }
  int a = k % 9;
  int p = k / 9;
  int py = p >> 6, px = p & 63;

  const double R[3] = {0.5, 1.0, 2.0};
  const double S[3] = {8.0, 16.0, 32.0};
  double r = R[a / 3], s = S[a - (a / 3) * 3];
  double hd = 16.0 * s * sqrt(r);
  double wd = 16.0 * s * sqrt(1.0 / r);
  float ay1 = (float)(8.0 - hd / 2.0) + (float)(py * 16);
  float ax1 = (float)(8.0 - wd / 2.0) + (float)(px * 16);
  float ay2 = (float)(8.0 + hd / 2.0) + (float)(py * 16);
  float ax2 = (float)(8.0 + wd / 2.0) + (float)(px * 16);
  if (n == 0) {
    float* ao = anchor_out + (size_t)k * 4;
    ao[0] = ay1; ao[1] = ax1; ao[2] = ay2; ao[3] = ax2;
  }
  float ahk = ay2 - ay1, awk = ax2 - ax1;
  float acy = ay1 + 0.5f * ahk, acx = ax1 + 0.5f * awk;
  const float* lp = out0 + ((size_t)(n * NANCH + k) << 2);
  float dy = lp[0], dx = lp[1], dh = lp[2], dw = lp[3];
  float cy = dy * ahk + acy;
  float cx = dx * awk + acx;
  float bh = expf(dh) * ahk;
  float bw = expf(dw) * awk;
  float img_h = (float)imgh_p[0], img_w = (float)imgw_p[0];
  float y1 = fminf(fmaxf(cy - 0.5f * bh, 0.f), img_h);
  float x1 = fminf(fmaxf(cx - 0.5f * bw, 0.f), img_w);
  float y2 = fminf(fmaxf(cy + 0.5f * bh, 0.f), img_h);
  float x2 = fminf(fmaxf(cx + 0.5f * bw, 0.f), img_w);
  bool valid = ((y2 - y1) >= 16.f) && ((x2 - x1) >= 16.f);
  float sc = valid ? fgbuf[n * NANCH + k] : -INFINITY;
  roibuf[n * NANCH + k] = make_float4(y1, x1, y2, x2);
  unsigned int b = __float_as_uint(sc);
  unsigned int m = b ^ ((b & 0x80000000u) ? 0xFFFFFFFFu : 0x80000000u);
  keys[gid] = ((u64)(~m) << 32) | (unsigned int)k;
}

// ---------------------------------------------------------------------------
// 5. bitonic sort (u64 keys, ascending per 65536 segment), 11 launches
// ---------------------------------------------------------------------------
__global__ __launch_bounds__(256) void sort_local_a(u64* __restrict__ keys) {
  __shared__ u64 sk[4096];
  const int base = blockIdx.x << 12;
  for (int e = threadIdx.x; e < 4096; e += 256) sk[e] = keys[base + e];
  __syncthreads();
  for (int k = 2; k <= 4096; k <<= 1) {
    for (int j = k >> 1; j > 0; j >>= 1) {
      for (int t = threadIdx.x; t < 2048; t += 256) {
        int l = ((t & ~(j - 1)) << 1) | (t & (j - 1));
        int rr = l | j;
        bool asc = (((base + l) & k) == 0);
        u64 a = sk[l], b = sk[rr];
        if ((a > b) == asc) { sk[l] = b; sk[rr] = a; }
      }
      __syncthreads();
    }
  }
  for (int e = threadIdx.x; e < 4096; e += 256) keys[base + e] = sk[e];
}

__global__ __launch_bounds__(256) void sort_global_pass(u64* __restrict__ keys,
                                                        int k, int j) {
  int t = blockIdx.x * 256 + threadIdx.x;
  int l = ((t & ~(j - 1)) << 1) | (t & (j - 1));
  int rr = l | j;
  bool asc = (((l & (SEG - 1)) & k) == 0);
  u64 a = keys[l], b = keys[rr];
  if ((a > b) == asc) { keys[l] = b; keys[rr] = a; }
}

__global__ __launch_bounds__(256) void sort_global_pass2(u64* __restrict__ keys,
                                                         int k, int j1) {
  int t = blockIdx.x * 256 + threadIdx.x;
  int j2 = j1 >> 1;
  int l = ((t & ~(j2 - 1)) << 1) | (t & (j2 - 1));
  l = ((l & ~(j1 - 1)) << 1) | (l & (j1 - 1));
  u64 e0 = keys[l], e1 = keys[l | j2], e2 = keys[l | j1], e3 = keys[l | j1 | j2];
  bool asc = (((l & (SEG - 1)) & k) == 0);
  u64 tmp;
  if ((e0 > e2) == asc) { tmp = e0; e0 = e2; e2 = tmp; }
  if ((e1 > e3) == asc) { tmp = e1; e1 = e3; e3 = tmp; }
  if ((e0 > e1) == asc) { tmp = e0; e0 = e1; e1 = tmp; }
  if ((e2 > e3) == asc) { tmp = e2; e2 = e3; e3 = tmp; }
  keys[l] = e0; keys[l | j2] = e1; keys[l | j1] = e2; keys[l | j1 | j2] = e3;
}

__global__ __launch_bounds__(256) void sort_local_b(u64* __restrict__ keys, int k) {
  __shared__ u64 sk[4096];
  const int base = blockIdx.x << 12;
  for (int e = threadIdx.x; e < 4096; e += 256) sk[e] = keys[base + e];
  __syncthreads();
  for (int j = 2048; j > 0; j >>= 1) {
    for (int t = threadIdx.x; t < 2048; t += 256) {
      int l = ((t & ~(j - 1)) << 1) | (t & (j - 1));
      int rr = l | j;
      bool asc = ((((base + l) & (SEG - 1)) & k) == 0);
      u64 a = sk[l], b = sk[rr];
      if ((a > b) == asc) { sk[l] = b; sk[rr] = a; }
    }
    __syncthreads();
  }
  for (int e = threadIdx.x; e < 4096; e += 256) keys[base + e] = sk[e];
}

// ---------------------------------------------------------------------------
// 6a. gather sorted boxes + alive bitmask words. grid (24, 2), block 256.
// ---------------------------------------------------------------------------
__global__ __launch_bounds__(256) void nms_gather(
    const u64* __restrict__ keys, const float4* __restrict__ roibuf,
    float4* __restrict__ sbox, u64* __restrict__ alive) {
  const int n = blockIdx.y;
  int i = blockIdx.x * 256 + threadIdx.x;  // 0..6143
  u64 kk = (i < N_PRE) ? keys[(n << 16) + i] : ~0ull;
  bool valid = ((unsigned)(kk >> 32)) < 0xFF800000u;
  float4 b = make_float4(0.f, 0.f, 0.f, 0.f);
  if (valid) b = roibuf[(size_t)n * NANCH + (unsigned)(kk & 0xFFFFFFFFull)];
  sbox[n * NPADC + i] = b;
  u64 bal = __ballot(valid);
  if ((threadIdx.x & 63) == 0) alive[n * NW + (i >> 6)] = bal;
}

// ---------------------------------------------------------------------------
// 6b. build FULL suppression matrix (both triangles; symmetric).
// M[n][i][w] bit b = IoU(box i, box 64w+b) > 0.7.
// grid (96 row-groups, 4 w-quarters, 2 n), block 256 (4 waves, wave wv does
// w = q*24 + it*4 + wv). Per-wave LDS staging, no barriers needed.
// ---------------------------------------------------------------------------
__global__ __launch_bounds__(256) void build_mask(
    const float4* __restrict__ sbox, u64* __restrict__ M) {
  __shared__ float4 jb[4][64];
  __shared__ float ja[4][64];
  const int tid = threadIdx.x, lane = tid & 63, wv = tid >> 6;
  const int g = blockIdx.x, q = blockIdx.y, n = blockIdx.z;
  const float4* sb = sbox + n * NPADC;
  float4 bi = sb[(g << 6) + lane];
  float ai = (bi.z - bi.x) * (bi.w - bi.y);
  u64* Mrow = M + ((size_t)(n * NPADC + (g << 6) + lane)) * NW;
#pragma unroll
  for (int it = 0; it < 6; ++it) {
    int w = q * 24 + (it << 2) + wv;
    float4 bjl = sb[(w << 6) + lane];
    jb[wv][lane] = bjl;
    ja[wv][lane] = (bjl.z - bjl.x) * (bjl.w - bjl.y);
    // wave-coherent LDS: no cross-wave sharing, no barrier needed
    u64 bits = 0;
#pragma unroll 8
    for (int j = 0; j < 64; ++j) {
      float4 bj = jb[wv][j];
      float aj = ja[wv][j];
      float ih = fmaxf(fminf(bi.z, bj.z) - fmaxf(bi.x, bj.x), 0.f);
      float iw = fmaxf(fminf(bi.w, bj.w) - fmaxf(bi.y, bj.y), 0.f);
      float inter = ih * iw;
      bool bit = inter / (ai + aj - inter + 1e-9f) > 0.7f;
      bits |= ((u64)bit) << j;
    }
    Mrow[w] = bits;
  }
}

// ---------------------------------------------------------------------------
// 6c. serial greedy reduce, one wave per image. Rolling prefetch of diag
// word + sbox (next chunk), 8-wide batched OR loads (one vmcnt wait per
// chunk). Full matrix -> unconditional ORs.
// ---------------------------------------------------------------------------
__global__ __launch_bounds__(64) void nms_reduce(
    const u64* __restrict__ M, const u64* __restrict__ alive,
    const float4* __restrict__ sbox, float* __restrict__ out) {
  const int n = blockIdx.x, lane = threadIdx.x;
  float* rois = out + O2 + n * (N_POST * 4);
  float* vmask = out + O5 + n * N_POST;
  const u64* A = alive + n * NW;
  const u64* Mb = M + (size_t)n * NPADC * NW;
  const float4* sb = sbox + n * NPADC;
  u64 aw0 = A[lane];
  u64 aw1 = (lane < 32) ? A[64 + lane] : 0ull;
  u64 accA = 0, accB = 0;   // lane L: suppressed words L and 64+L (L<32)
  int nk = 0;
  u64 dnext = Mb[(size_t)lane * NW + 0];
  float4 bnext = sb[lane];
  const u64 below = lane ? (~0ull >> (64 - lane)) : 0ull;

  for (int c = 0; c < 94; ++c) {
    u64 dcur = dnext;
    float4 bcur = bnext;
    if (c + 1 < 94) {
      dnext = Mb[(size_t)(((c + 1) << 6) + lane) * NW + (c + 1)];
      bnext = sb[((c + 1) << 6) + lane];
    }
    u64 wacc = (c < 64) ? bcast64(accA, c) : bcast64(accB, c - 64);
    u64 aw = (c < 64) ? bcast64(aw0, c) : bcast64(aw1, c - 64);
    u64 alive_u = aw & ~wacc;
    if (alive_u == 0ull) continue;

    u64 dmask = dcur & below;  // suppressors j < lane within chunk
    u64 rem = alive_u, kept = 0;
    while (rem) {
      int j = __builtin_ctzll(rem);          // uniform across wave
      kept |= 1ull << j;
      u64 col = __ballot((dmask >> j) & 1);  // who j suppresses (i > j)
      rem &= ~(col | (1ull << j));
    }

    int npop = __popcll(kept);
    if ((kept >> lane) & 1ull) {
      int slot = nk + __popcll(kept & below);
      if (slot < N_POST) {
        rois[slot * 4 + 0] = bcur.x; rois[slot * 4 + 1] = bcur.y;
        rois[slot * 4 + 2] = bcur.z; rois[slot * 4 + 3] = bcur.w;
        vmask[slot] = 1.0f;
      }
    }
    if (nk + npop >= N_POST) break;
    nk += npop;

    // 8-wide batched OR of kept rows: 8 independent loads -> one wait
    u64 kk = kept;
    while (kk) {
      int j0 = __builtin_ctzll(kk); kk &= kk - 1;
      int j1 = kk ? __builtin_ctzll(kk) : j0; kk &= kk - 1;
      int j2 = kk ? __builtin_ctzll(kk) : j0; kk &= kk - 1;
      int j3 = kk ? __builtin_ctzll(kk) : j0; kk &= kk - 1;
      int j4 = kk ? __builtin_ctzll(kk) : j0; kk &= kk - 1;
      int j5 = kk ? __builtin_ctzll(kk) : j0; kk &= kk - 1;
      int j6 = kk ? __builtin_ctzll(kk) : j0; kk &= kk - 1;
      int j7 = kk ? __builtin_ctzll(kk) : j0; kk &= kk - 1;
      const u64* r0 = Mb + (size_t)((c << 6) + j0) * NW;
      const u64* r1 = Mb + (size_t)((c << 6) + j1) * NW;
      const u64* r2 = Mb + (size_t)((c << 6) + j2) * NW;
      const u64* r3 = Mb + (size_t)((c << 6) + j3) * NW;
      const u64* r4 = Mb + (size_t)((c << 6) + j4) * NW;
      const u64* r5 = Mb + (size_t)((c << 6) + j5) * NW;
      const u64* r6 = Mb + (size_t)((c << 6) + j6) * NW;
      const u64* r7 = Mb + (size_t)((c << 6) + j7) * NW;
      u64 oA = r0[lane] | r1[lane] | r2[lane] | r3[lane]
             | r4[lane] | r5[lane] | r6[lane] | r7[lane];
      u64 oB = 0;
      if (lane < 32)
        oB = r0[64 + lane] | r1[64 + lane] | r2[64 + lane] | r3[64 + lane]
           | r4[64 + lane] | r5[64 + lane] | r6[64 + lane] | r7[64 + lane];
      accA |= oA;
      accB |= oB;
    }
  }
}

// ---------------------------------------------------------------------------
extern "C" void kernel_launch(void* const* d_in, const int* in_sizes, int n_in,
                              void* d_out, int out_size, void* d_ws, size_t ws_size,
                              hipStream_t stream) {
  const float* x        = (const float*)d_in[0];
  const float* conv1_w  = (const float*)d_in[1];
  const float* conv1_b  = (const float*)d_in[2];
  const float* score_w  = (const float*)d_in[3];
  const float* score_b  = (const float*)d_in[4];
  const float* loc_w    = (const float*)d_in[5];
  const float* loc_b    = (const float*)d_in[6];
  const int*   imgh_p   = (const int*)d_in[7];
  const int*   imgw_p   = (const int*)d_in[8];

  float* out = (float*)d_out;
  float* ws  = (float*)d_ws;

  _Float16* xhi = (_Float16*)(ws + WS_XHI);
  _Float16* xlo = (_Float16*)(ws + WS_XLO);
  _Float16* whi = (_Float16*)(ws + WS_WHI);
  _Float16* wlo = (_Float16*)(ws + WS_WLO);
  float* wslt   = ws + WS_WSLT;
  float* wslb   = ws + WS_WSLB;
  float* hbuf   = ws + WS_H;
  float* guard  = ws + WS_GUARD;
  // overlays (xhi region is dead after conv)
  float* fgbuf   = ws + WS_FG;
  float4* roibuf = (float4*)(ws + WS_ROI);
  u64* keys      = (u64*)(ws + WS_KEYS);
  float4* sbox   = (float4*)(ws + WS_SBOX);
  u64* alive     = (u64*)(ws + WS_ALIVE);
  u64* maskbuf   = (u64*)(ws + WS_MASK);   // overlays whi/wlo (dead after conv)

  prep_all<<<5826, 256, 0, stream>>>(x, conv1_w, loc_w, score_w, loc_b, score_b,
                                     (float4*)hbuf, (float4*)guard,
                                     xhi, xlo, whi, wlo, wslt, wslb);

  conv_mfma<<<dim3(64, 4, 3), 256, 0, stream>>>(xhi, xlo, whi, wlo, guard, hbuf);

  head_kernel<<<dim3(64, 2), 256, 0, stream>>>(hbuf, conv1_b, wslt, wslb, out, fgbuf);
  decode_kernel<<<512, 256, 0, stream>>>(out, fgbuf, roibuf, keys,
                                         out + O4, out, imgh_p, imgw_p);

  sort_local_a<<<32, 256, 0, stream>>>(keys);
  for (int k = 8192; k <= SEG; k <<= 1) {
    int j = k >> 1;
    while (j >= 4096) {
      if (j >= 8192) {
        sort_global_pass2<<<128, 256, 0, stream>>>(keys, k, j);
        j >>= 2;
      } else {
        sort_global_pass<<<256, 256, 0, stream>>>(keys, k, j);
        j >>= 1;
      }
    }
    sort_local_b<<<32, 256, 0, stream>>>(keys, k);
  }

  nms_gather<<<dim3(24, 2), 256, 0, stream>>>(keys, roibuf, sbox, alive);
  build_mask<<<dim3(96, 4, 2), 256, 0, stream>>>(sbox, maskbuf);
  nms_reduce<<<2, 64, 0, stream>>>(maskbuf, alive, sbox, out);
}

// Round 3
// 544.042 us; speedup vs baseline: 1.0850x; 1.0850x over previous
//
#include <hip/hip_runtime.h>
#include <hip/hip_bf16.h>
#include <math.h>
#include <cstdint>

typedef unsigned long long u64;
typedef unsigned int u32;
typedef _Float16 half8 __attribute__((ext_vector_type(8)));
typedef float floatx4 __attribute__((ext_vector_type(4)));

// ---------------------------------------------------------------------------
// Sizes
// ---------------------------------------------------------------------------
#define NANCH 36864        // 4096*9
#define SEG 65536          // padded per-image sort segment
#define N_PRE 6000
#define N_POST 300
#define NW 96              // mask words per row (6144 bits)
#define NPADC 6144         // padded candidate count

// output float offsets
#define O0 0               // rpn_locs  2*36864*4 = 294912
#define O1 294912          // rpn_scores 2*36864*2 = 147456
#define O2 442368          // rois 2*300*4 = 2400
#define O3 444768          // roi_indices 600
#define O4 445368          // anchor 147456
#define O5 592824          // vmask 600

// workspace float offsets
#define WS_XHI   0                        // xhi f16 [2][4096][512] (2,097,152 f)
#define WS_XLO   2097152
#define WS_WHI   4194304                  // whi f16 [9][512][512] (1,179,648 f)
#define WS_WLO   5373952
#define WS_WSLT  6553600                  // 32768
#define WS_WSLB  6586368                  // 64
#define WS_H     6586432                  // hbuf f32 [2][4096][512] = 4,194,304 f
#define WS_GUARD 10780736                 // 64 floats of zeros (OOB target)
// overlays into dead XHI region (used only after conv completes):
#define WS_FG    0                        // 73728
#define WS_ROI   73728                    // 294912 (16B aligned)
#define WS_KEYS  368640                   // 131072 u64 = 262144 f
#define WS_SBOX  630784                   // 2*6144 float4 = 49152 f
#define WS_ALIVE 679936                   // 2*96 u64 = 384 f
// overlay into dead WHI+WLO region (after conv): FULL suppression matrix
#define WS_MASK  4194304                  // 2*6144*96 u64 = 9,437,184 B (exact fit)

#define HSCALE 9.5367431640625e-07f       // 2^-20

// ---------------------------------------------------------------------------
__device__ __forceinline__ void gl_lds16(const void* g, void* l) {
  __builtin_amdgcn_global_load_lds(
      (const __attribute__((address_space(1))) u32*)g,
      (__attribute__((address_space(3))) u32*)l, 16, 0, 0);
}

__device__ __forceinline__ u64 bcast64(u64 v, int src) {
  u32 lo = (u32)__shfl((int)(v & 0xFFFFFFFFull), src);
  u32 hi = (u32)__shfl((int)(v >> 32), src);
  return ((u64)hi << 32) | lo;
}

// ---------------------------------------------------------------------------
// 0. fused prep: zero hbuf+guard | xcvt | wcvt | head-weight pack.
// Linear grid: [0,4097) zero, [4097,5121) xcvt, [5121,5697) wcvt,
// [5697,5826) prep_small.
// ---------------------------------------------------------------------------
__global__ __launch_bounds__(256) void prep_all(
    const float* __restrict__ x, const float* __restrict__ w,
    const float* __restrict__ lw, const float* __restrict__ sw,
    const float* __restrict__ lb, const float* __restrict__ sb,
    float4* __restrict__ h, float4* __restrict__ guard,
    _Float16* __restrict__ xhi, _Float16* __restrict__ xlo,
    _Float16* __restrict__ whi, _Float16* __restrict__ wlo,
    float* __restrict__ wslt, float* __restrict__ wslb) {
  __shared__ float s[64 * 65];
  const int b = blockIdx.x, tid = threadIdx.x;
  if (b < 4097) {
    int idx = b * 256 + tid;
    if (idx < 1048576) h[idx] = make_float4(0.f, 0.f, 0.f, 0.f);
    else if (idx < 1048576 + 16) guard[idx - 1048576] = make_float4(0.f, 0.f, 0.f, 0.f);
    return;
  }
  if (b < 5121) {  // xcvt: [n][c][pix] f32 -> [n][pix][c] f16 hi/lo x1024
    int l = b - 4097;
    int pt = l & 63, cg = (l >> 6) & 7, n = l >> 9;
    const int c0 = cg << 6, p0 = pt << 6;
#pragma unroll
    for (int kk = 0; kk < 16; ++kk) {
      int e = tid + (kk << 8);
      int ci = e >> 6, pi = e & 63;
      s[ci * 65 + pi] = x[(((size_t)(n * 512 + c0 + ci)) << 12) + p0 + pi];
    }
    __syncthreads();
#pragma unroll
    for (int kk = 0; kk < 16; ++kk) {
      int e = tid + (kk << 8);
      int ci = e & 63, pi = e >> 6;
      float sv = s[ci * 65 + pi] * 1024.f;
      _Float16 hi = (_Float16)sv;
      _Float16 lo = (_Float16)(sv - (float)hi);
      size_t off = (((size_t)(n << 12) + p0 + pi) << 9) + c0 + ci;
      xhi[off] = hi;
      xlo[off] = lo;
    }
    return;
  }
  if (b < 5697) {  // wcvt: [o][c][3][3] -> [t][o][c] f16 hi/lo x1024
    int l = b - 5121;
    int ct = l & 7, ot = (l >> 3) & 7, t = l >> 6;
    const int c0 = ct << 6, o0 = ot << 6;
#pragma unroll
    for (int kk = 0; kk < 16; ++kk) {
      int e = tid + (kk << 8);
      int ci = e & 63, oi = e >> 6;
      float sv = w[(size_t)(o0 + oi) * 4608 + (c0 + ci) * 9 + t] * 1024.f;
      _Float16 hi = (_Float16)sv;
      _Float16 lo = (_Float16)(sv - (float)hi);
      size_t off = ((size_t)((t << 9) + o0 + oi) << 9) + c0 + ci;
      whi[off] = hi;
      wlo[off] = lo;
    }
    return;
  }
  {  // prep_small
    int e = (b - 5697) * 256 + tid;
    if (e < 32768) {
      int c = e >> 6, o = e & 63;
      float v = 0.f;
      if (o < 36) v = lw[o * 512 + c];
      else if (o < 54) v = sw[(o - 36) * 512 + c];
      wslt[e] = v;
    } else if (e < 32832) {
      int o = e - 32768;
      float v = 0.f;
      if (o < 36) v = lb[o];
      else if (o < 54) v = sb[o - 36];
      wslb[o] = v;
    }
  }
}

// ---------------------------------------------------------------------------
// 1. MFMA implicit-GEMM 3x3 conv (fp16x2 split: hh + hl + lh, fp32 acc).
// R7: B (weights) moved from LDS staging to per-lane REGISTER loads.
// The B MFMA fragment is per-lane addressable (row o0+wo+in*16+l15, cols
// c0+l16*8..+8 = one aligned 16B load), so B never needed LDS or a
// barrier. R0's 2-barriers-per-tap (the vmcnt(0) drain before each tap's
// MFMA burst, ~4000cy per tap vs 230cy of MFMA) drop to 2 barriers per
// 32-channel step, amortized over 9 taps x 48 MFMA. B is double-buffered
// one tap ahead in registers inside a fully-unrolled tap loop; plain
// global loads let the compiler issue counted vmcnt waits (no barrier in
// the way — unlike R1, where the barrier defeated the pipeline).
// History: R0 121us (2-barrier/tap) | R1 129us (pipelined, +barrier) |
// R2 217us (pass-split, 16 MFMA/barrier).
// ---------------------------------------------------------------------------
__global__ __launch_bounds__(256) void conv_mfma(
    const _Float16* __restrict__ xhi, const _Float16* __restrict__ xlo,
    const _Float16* __restrict__ whi, const _Float16* __restrict__ wlo,
    const float* __restrict__ guard, float* __restrict__ hout) {
  __shared__ _Float16 aHi[4 * 68 * 32];
  __shared__ _Float16 aLo[4 * 68 * 32];
  const int tid = threadIdx.x;
  const int lane = tid & 63, w = tid >> 6;
  const int ptile = blockIdx.x;
  const int og = blockIdx.y;
  const int kq = blockIdx.z;
  const int n = ptile >> 5;
  const int y0 = (ptile & 31) << 1;
  const int o0 = og << 7;
  const int l15 = lane & 15, l16 = lane >> 4;
  const int ry = w >> 1;
  const int wo = (w & 1) << 6;

  floatx4 acc[4][4];
#pragma unroll
  for (int a = 0; a < 4; ++a)
#pragma unroll
    for (int b = 0; b < 4; ++b) acc[a][b] = (floatx4)0.f;

  // per-lane B element offset (halves): row (o0+wo+in*16+l15) * 512 + l16*8
  const size_t bbase = ((size_t)(o0 + wo + l15) << 9) + (l16 << 3);

  half8 bh[2][4], bl[2][4];

  for (int s = 0; s < 8; ++s) {
    const int c0 = (kq << 8) + (s << 5);
    __syncthreads();                 // all waves done reading aS of prev s
    // stage A (input tile + halo) into LDS via DMA
    for (int i = w; i < 17; i += 4) {
      int chunk = (i << 6) + lane;
      int p = chunk >> 2, q = chunk & 3;
      int r = p / 68, xs = p - r * 68;
      int y = y0 - 1 + r, xg = xs - 1;
      bool ok = ((unsigned)y < 64u) && ((unsigned)xg < 64u);
      size_t off = (((size_t)(n << 12) + (y << 6) + xg) << 9) + c0 + (q << 3);
      const void* gh = ok ? (const void*)(xhi + off) : (const void*)guard;
      const void* gl = ok ? (const void*)(xlo + off) : (const void*)guard;
      gl_lds16(gh, (char*)aHi + (i << 10));
      gl_lds16(gl, (char*)aLo + (i << 10));
    }
    // prefetch B(tt=0) into registers (overlaps the A drain)
    {
      const size_t base0 = bbase + c0;   // tt=0
#pragma unroll
      for (int in = 0; in < 4; ++in) {
        size_t off = base0 + ((size_t)in << 13);   // in*16 rows * 512
        bh[0][in] = *(const half8*)(whi + off);
        bl[0][in] = *(const half8*)(wlo + off);
      }
    }
    __syncthreads();                 // vmcnt(0) drain: A in LDS (B0 ready too)

#pragma unroll
    for (int tt = 0; tt < 9; ++tt) {
      const int cur = tt & 1, nxt = (tt + 1) & 1;
      if (tt < 8) {  // prefetch next tap's B; stays in flight across MFMAs
        const size_t basen = ((size_t)(tt + 1) << 18) + bbase + c0;
#pragma unroll
        for (int in = 0; in < 4; ++in) {
          size_t off = basen + ((size_t)in << 13);
          bh[nxt][in] = *(const half8*)(whi + off);
          bl[nxt][in] = *(const half8*)(wlo + off);
        }
      }
      const int dy = tt / 3, dx = tt - 3 * dy;
      half8 av[4], alv[4];
#pragma unroll
      for (int im = 0; im < 4; ++im) {
        int xp = (im << 4) + l15;
        int p = (ry + dy) * 68 + xp + dx;
        av[im] = *(const half8*)&aHi[(p << 5) + (l16 << 3)];
        alv[im] = *(const half8*)&aLo[(p << 5) + (l16 << 3)];
      }
#pragma unroll
      for (int im = 0; im < 4; ++im)
#pragma unroll
        for (int in = 0; in < 4; ++in) {
          acc[im][in] = __builtin_amdgcn_mfma_f32_16x16x32_f16(
              av[im], bh[cur][in], acc[im][in], 0, 0, 0);
          acc[im][in] = __builtin_amdgcn_mfma_f32_16x16x32_f16(
              av[im], bl[cur][in], acc[im][in], 0, 0, 0);
          acc[im][in] = __builtin_amdgcn_mfma_f32_16x16x32_f16(
              alv[im], bh[cur][in], acc[im][in], 0, 0, 0);
        }
    }
  }

#pragma unroll
  for (int im = 0; im < 4; ++im)
#pragma unroll
    for (int in = 0; in < 4; ++in) {
      int o = o0 + wo + (in << 4) + l15;
#pragma unroll
      for (int reg = 0; reg < 4; ++reg) {
        int m_local = (ry << 6) + (im << 4) + (l16 << 2) + reg;
        size_t off = (((size_t)(n << 12) + (y0 << 6) + m_local) << 9) + o;
        atomicAdd(&hout[off], acc[im][in][reg]);
      }
    }
}

// ---------------------------------------------------------------------------
// 2. 1x1 heads + softmax. grid (64 y, 2 n), block 256.
// ---------------------------------------------------------------------------
__global__ __launch_bounds__(256) void head_kernel(
    const float* __restrict__ hbuf, const float* __restrict__ cb,
    const float* __restrict__ wslt, const float* __restrict__ wslb,
    float* __restrict__ out, float* __restrict__ fgbuf) {
  const int y = blockIdx.x, n = blockIdx.y;
  __shared__ float sH[16 * 65];
  __shared__ float sWt[1024];
  __shared__ float sOut[64 * 65];
  const int tid = threadIdx.x;
  const int x = tid & 63, og = tid >> 6;

  float acc[16];
#pragma unroll
  for (int j = 0; j < 16; ++j) acc[j] = 0.f;

  const float* hb = hbuf + (((size_t)(n << 12) + (y << 6)) << 9);

  for (int c0 = 0; c0 < 512; c0 += 16) {
    __syncthreads();
#pragma unroll
    for (int p = 0; p < 4; ++p) {
      int e = tid + (p << 8);
      {
        int cc = e & 15, xx = e >> 4;
        float raw = hb[((size_t)xx << 9) + c0 + cc];
        sH[cc * 65 + xx] = fmaxf(raw * HSCALE + cb[c0 + cc], 0.f);
      }
      {
        int cc = e >> 6, xx = e & 63;
        sWt[e] = wslt[((c0 + cc) << 6) + xx];
      }
    }
    __syncthreads();
#pragma unroll
    for (int cc = 0; cc < 16; ++cc) {
      float hv = sH[cc * 65 + x];
      const float4* wp = (const float4*)&sWt[(cc << 6) + (og << 4)];
      float4 w0 = wp[0], w1 = wp[1], w2 = wp[2], w3 = wp[3];
      acc[0]  = fmaf(hv, w0.x, acc[0]);  acc[1]  = fmaf(hv, w0.y, acc[1]);
      acc[2]  = fmaf(hv, w0.z, acc[2]);  acc[3]  = fmaf(hv, w0.w, acc[3]);
      acc[4]  = fmaf(hv, w1.x, acc[4]);  acc[5]  = fmaf(hv, w1.y, acc[5]);
      acc[6]  = fmaf(hv, w1.z, acc[6]);  acc[7]  = fmaf(hv, w1.w, acc[7]);
      acc[8]  = fmaf(hv, w2.x, acc[8]);  acc[9]  = fmaf(hv, w2.y, acc[9]);
      acc[10] = fmaf(hv, w2.z, acc[10]); acc[11] = fmaf(hv, w2.w, acc[11]);
      acc[12] = fmaf(hv, w3.x, acc[12]); acc[13] = fmaf(hv, w3.y, acc[13]);
      acc[14] = fmaf(hv, w3.z, acc[14]); acc[15] = fmaf(hv, w3.w, acc[15]);
    }
  }
  __syncthreads();
#pragma unroll
  for (int j = 0; j < 16; ++j) {
    int o = (og << 4) + j;
    sOut[o * 65 + x] = acc[j] + wslb[o];
  }
  __syncthreads();

  const int p0 = (n << 12) + (y << 6);
  float* locs = out + O0 + (size_t)p0 * 36;
  for (int e = tid; e < 2304; e += 256) {
    int xx = e / 36, o = e - xx * 36;
    locs[e] = sOut[o * 65 + xx];
  }
  float* scrs = out + O1 + (size_t)p0 * 18;
  for (int e = tid; e < 1152; e += 256) {
    int xx = e / 18, ss = e - xx * 18;
    scrs[e] = sOut[(36 + ss) * 65 + xx];
  }
  float* fg = fgbuf + n * NANCH + (y << 6) * 9;
  for (int e = tid; e < 576; e += 256) {
    int xx = e / 9, a = e - xx * 9;
    float s0 = sOut[(36 + 2 * a) * 65 + xx];
    float s1 = sOut[(36 + 2 * a + 1) * 65 + xx];
    fg[e] = 1.0f / (1.0f + expf(s0 - s1));
  }
}

// ---------------------------------------------------------------------------
// 3. anchors + decode + clip + min-size + sort keys (+ init out regions).
// ---------------------------------------------------------------------------
__global__ __launch_bounds__(256) void decode_kernel(
    const float* __restrict__ out0, const float* __restrict__ fgbuf,
    float4* __restrict__ roibuf, u64* __restrict__ keys,
    float* __restrict__ anchor_out, float* __restrict__ out,
    const int* __restrict__ imgh_p, const int* __restrict__ imgw_p) {
  int gid = blockIdx.x * 256 + threadIdx.x;   // < 131072
  if (gid < 3600) {
    if (gid < 2400) out[O2 + gid] = 0.f;
    else if (gid < 3000) out[O3 + (gid - 2400)] = (float)((gid - 2400) / 300);
    else out[O5 + (gid - 3000)] = 0.f;
  }
  int n = gid >> 16, k = gid & (SEG - 1);
  if (k >= NANCH) { keys[gid] = ~0ull; return; }
  int a = k % 9;
  int p = k / 9;
  int py = p >> 6, px = p & 63;

  const double R[3] = {0.5, 1.0, 2.0};
  const double S[3] = {8.0, 16.0, 32.0};
  double r = R[a / 3], s = S[a - (a / 3) * 3];
  double hd = 16.0 * s * sqrt(r);
  double wd = 16.0 * s * sqrt(1.0 / r);
  float ay1 = (float)(8.0 - hd / 2.0) + (float)(py * 16);
  float ax1 = (float)(8.0 - wd / 2.0) + (float)(px * 16);
  float ay2 = (float)(8.0 + hd / 2.0) + (float)(py * 16);
  float ax2 = (float)(8.0 + wd / 2.0) + (float)(px * 16);
  if (n == 0) {
    float* ao = anchor_out + (size_t)k * 4;
    ao[0] = ay1; ao[1] = ax1; ao[2] = ay2; ao[3] = ax2;
  }
  float ahk = ay2 - ay1, awk = ax2 - ax1;
  float acy = ay1 + 0.5f * ahk, acx = ax1 + 0.5f * awk;
  const float* lp = out0 + ((size_t)(n * NANCH + k) << 2);
  float dy = lp[0], dx = lp[1], dh = lp[2], dw = lp[3];
  float cy = dy * ahk + acy;
  float cx = dx * awk + acx;
  float bh = expf(dh) * ahk;
  float bw = expf(dw) * awk;
  float img_h = (float)imgh_p[0], img_w = (float)imgw_p[0];
  float y1 = fminf(fmaxf(cy - 0.5f * bh, 0.f), img_h);
  float x1 = fminf(fmaxf(cx - 0.5f * bw, 0.f), img_w);
  float y2 = fminf(fmaxf(cy + 0.5f * bh, 0.f), img_h);
  float x2 = fminf(fmaxf(cx + 0.5f * bw, 0.f), img_w);
  bool valid = ((y2 - y1) >= 16.f) && ((x2 - x1) >= 16.f);
  float sc = valid ? fgbuf[n * NANCH + k] : -INFINITY;
  roibuf[n * NANCH + k] = make_float4(y1, x1, y2, x2);
  unsigned int b = __float_as_uint(sc);
  unsigned int m = b ^ ((b & 0x80000000u) ? 0xFFFFFFFFu : 0x80000000u);
  keys[gid] = ((u64)(~m) << 32) | (unsigned int)k;
}

// ---------------------------------------------------------------------------
// 5. bitonic sort (u64 keys, ascending per 65536 segment), 11 launches
// ---------------------------------------------------------------------------
__global__ __launch_bounds__(256) void sort_local_a(u64* __restrict__ keys) {
  __shared__ u64 sk[4096];
  const int base = blockIdx.x << 12;
  for (int e = threadIdx.x; e < 4096; e += 256) sk[e] = keys[base + e];
  __syncthreads();
  for (int k = 2; k <= 4096; k <<= 1) {
    for (int j = k >> 1; j > 0; j >>= 1) {
      for (int t = threadIdx.x; t < 2048; t += 256) {
        int l = ((t & ~(j - 1)) << 1) | (t & (j - 1));
        int rr = l | j;
        bool asc = (((base + l) & k) == 0);
        u64 a = sk[l], b = sk[rr];
        if ((a > b) == asc) { sk[l] = b; sk[rr] = a; }
      }
      __syncthreads();
    }
  }
  for (int e = threadIdx.x; e < 4096; e += 256) keys[base + e] = sk[e];
}

__global__ __launch_bounds__(256) void sort_global_pass(u64* __restrict__ keys,
                                                        int k, int j) {
  int t = blockIdx.x * 256 + threadIdx.x;
  int l = ((t & ~(j - 1)) << 1) | (t & (j - 1));
  int rr = l | j;
  bool asc = (((l & (SEG - 1)) & k) == 0);
  u64 a = keys[l], b = keys[rr];
  if ((a > b) == asc) { keys[l] = b; keys[rr] = a; }
}

__global__ __launch_bounds__(256) void sort_global_pass2(u64* __restrict__ keys,
                                                         int k, int j1) {
  int t = blockIdx.x * 256 + threadIdx.x;
  int j2 = j1 >> 1;
  int l = ((t & ~(j2 - 1)) << 1) | (t & (j2 - 1));
  l = ((l & ~(j1 - 1)) << 1) | (l & (j1 - 1));
  u64 e0 = keys[l], e1 = keys[l | j2], e2 = keys[l | j1], e3 = keys[l | j1 | j2];
  bool asc = (((l & (SEG - 1)) & k) == 0);
  u64 tmp;
  if ((e0 > e2) == asc) { tmp = e0; e0 = e2; e2 = tmp; }
  if ((e1 > e3) == asc) { tmp = e1; e1 = e3; e3 = tmp; }
  if ((e0 > e1) == asc) { tmp = e0; e0 = e1; e1 = tmp; }
  if ((e2 > e3) == asc) { tmp = e2; e2 = e3; e3 = tmp; }
  keys[l] = e0; keys[l | j2] = e1; keys[l | j1] = e2; keys[l | j1 | j2] = e3;
}

__global__ __launch_bounds__(256) void sort_local_b(u64* __restrict__ keys, int k) {
  __shared__ u64 sk[4096];
  const int base = blockIdx.x << 12;
  for (int e = threadIdx.x; e < 4096; e += 256) sk[e] = keys[base + e];
  __syncthreads();
  for (int j = 2048; j > 0; j >>= 1) {
    for (int t = threadIdx.x; t < 2048; t += 256) {
      int l = ((t & ~(j - 1)) << 1) | (t & (j - 1));
      int rr = l | j;
      bool asc = ((((base + l) & (SEG - 1)) & k) == 0);
      u64 a = sk[l], b = sk[rr];
      if ((a > b) == asc) { sk[l] = b; sk[rr] = a; }
    }
    __syncthreads();
  }
  for (int e = threadIdx.x; e < 4096; e += 256) keys[base + e] = sk[e];
}

// ---------------------------------------------------------------------------
// 6a. gather sorted boxes + alive bitmask words. grid (24, 2), block 256.
// ---------------------------------------------------------------------------
__global__ __launch_bounds__(256) void nms_gather(
    const u64* __restrict__ keys, const float4* __restrict__ roibuf,
    float4* __restrict__ sbox, u64* __restrict__ alive) {
  const int n = blockIdx.y;
  int i = blockIdx.x * 256 + threadIdx.x;  // 0..6143
  u64 kk = (i < N_PRE) ? keys[(n << 16) + i] : ~0ull;
  bool valid = ((unsigned)(kk >> 32)) < 0xFF800000u;
  float4 b = make_float4(0.f, 0.f, 0.f, 0.f);
  if (valid) b = roibuf[(size_t)n * NANCH + (unsigned)(kk & 0xFFFFFFFFull)];
  sbox[n * NPADC + i] = b;
  u64 bal = __ballot(valid);
  if ((threadIdx.x & 63) == 0) alive[n * NW + (i >> 6)] = bal;
}

// ---------------------------------------------------------------------------
// 6b. build FULL suppression matrix (both triangles; symmetric).
// M[n][i][w] bit b = IoU(box i, box 64w+b) > 0.7.
// grid (96 row-groups, 4 w-quarters, 2 n), block 256 (4 waves, wave wv does
// w = q*24 + it*4 + wv). Per-wave LDS staging, no barriers needed.
// ---------------------------------------------------------------------------
__global__ __launch_bounds__(256) void build_mask(
    const float4* __restrict__ sbox, u64* __restrict__ M) {
  __shared__ float4 jb[4][64];
  __shared__ float ja[4][64];
  const int tid = threadIdx.x, lane = tid & 63, wv = tid >> 6;
  const int g = blockIdx.x, q = blockIdx.y, n = blockIdx.z;
  const float4* sb = sbox + n * NPADC;
  float4 bi = sb[(g << 6) + lane];
  float ai = (bi.z - bi.x) * (bi.w - bi.y);
  u64* Mrow = M + ((size_t)(n * NPADC + (g << 6) + lane)) * NW;
#pragma unroll
  for (int it = 0; it < 6; ++it) {
    int w = q * 24 + (it << 2) + wv;
    float4 bjl = sb[(w << 6) + lane];
    jb[wv][lane] = bjl;
    ja[wv][lane] = (bjl.z - bjl.x) * (bjl.w - bjl.y);
    // wave-coherent LDS: no cross-wave sharing, no barrier needed
    u64 bits = 0;
#pragma unroll 8
    for (int j = 0; j < 64; ++j) {
      float4 bj = jb[wv][j];
      float aj = ja[wv][j];
      float ih = fmaxf(fminf(bi.z, bj.z) - fmaxf(bi.x, bj.x), 0.f);
      float iw = fmaxf(fminf(bi.w, bj.w) - fmaxf(bi.y, bj.y), 0.f);
      float inter = ih * iw;
      bool bit = inter / (ai + aj - inter + 1e-9f) > 0.7f;
      bits |= ((u64)bit) << j;
    }
    Mrow[w] = bits;
  }
}

// ---------------------------------------------------------------------------
// 6c. serial greedy reduce, one wave per image. Rolling prefetch of diag
// word + sbox (next chunk), 8-wide batched OR loads (one vmcnt wait per
// chunk). Full matrix -> unconditional ORs.
// ---------------------------------------------------------------------------
__global__ __launch_bounds__(64) void nms_reduce(
    const u64* __restrict__ M, const u64* __restrict__ alive,
    const float4* __restrict__ sbox, float* __restrict__ out) {
  const int n = blockIdx.x, lane = threadIdx.x;
  float* rois = out + O2 + n * (N_POST * 4);
  float* vmask = out + O5 + n * N_POST;
  const u64* A = alive + n * NW;
  const u64* Mb = M + (size_t)n * NPADC * NW;
  const float4* sb = sbox + n * NPADC;
  u64 aw0 = A[lane];
  u64 aw1 = (lane < 32) ? A[64 + lane] : 0ull;
  u64 accA = 0, accB = 0;   // lane L: suppressed words L and 64+L (L<32)
  int nk = 0;
  u64 dnext = Mb[(size_t)lane * NW + 0];
  float4 bnext = sb[lane];
  const u64 below = lane ? (~0ull >> (64 - lane)) : 0ull;

  for (int c = 0; c < 94; ++c) {
    u64 dcur = dnext;
    float4 bcur = bnext;
    if (c + 1 < 94) {
      dnext = Mb[(size_t)(((c + 1) << 6) + lane) * NW + (c + 1)];
      bnext = sb[((c + 1) << 6) + lane];
    }
    u64 wacc = (c < 64) ? bcast64(accA, c) : bcast64(accB, c - 64);
    u64 aw = (c < 64) ? bcast64(aw0, c) : bcast64(aw1, c - 64);
    u64 alive_u = aw & ~wacc;
    if (alive_u == 0ull) continue;

    u64 dmask = dcur & below;  // suppressors j < lane within chunk
    u64 rem = alive_u, kept = 0;
    while (rem) {
      int j = __builtin_ctzll(rem);          // uniform across wave
      kept |= 1ull << j;
      u64 col = __ballot((dmask >> j) & 1);  // who j suppresses (i > j)
      rem &= ~(col | (1ull << j));
    }

    int npop = __popcll(kept);
    if ((kept >> lane) & 1ull) {
      int slot = nk + __popcll(kept & below);
      if (slot < N_POST) {
        rois[slot * 4 + 0] = bcur.x; rois[slot * 4 + 1] = bcur.y;
        rois[slot * 4 + 2] = bcur.z; rois[slot * 4 + 3] = bcur.w;
        vmask[slot] = 1.0f;
      }
    }
    if (nk + npop >= N_POST) break;
    nk += npop;

    // 8-wide batched OR of kept rows: 8 independent loads -> one wait
    u64 kk = kept;
    while (kk) {
      int j0 = __builtin_ctzll(kk); kk &= kk - 1;
      int j1 = kk ? __builtin_ctzll(kk) : j0; kk &= kk - 1;
      int j2 = kk ? __builtin_ctzll(kk) : j0; kk &= kk - 1;
      int j3 = kk ? __builtin_ctzll(kk) : j0; kk &= kk - 1;
      int j4 = kk ? __builtin_ctzll(kk) : j0; kk &= kk - 1;
      int j5 = kk ? __builtin_ctzll(kk) : j0; kk &= kk - 1;
      int j6 = kk ? __builtin_ctzll(kk) : j0; kk &= kk - 1;
      int j7 = kk ? __builtin_ctzll(kk) : j0; kk &= kk - 1;
      const u64* r0 = Mb + (size_t)((c << 6) + j0) * NW;
      const u64* r1 = Mb + (size_t)((c << 6) + j1) * NW;
      const u64* r2 = Mb + (size_t)((c << 6) + j2) * NW;
      const u64* r3 = Mb + (size_t)((c << 6) + j3) * NW;
      const u64* r4 = Mb + (size_t)((c << 6) + j4) * NW;
      const u64* r5 = Mb + (size_t)((c << 6) + j5) * NW;
      const u64* r6 = Mb + (size_t)((c << 6) + j6) * NW;
      const u64* r7 = Mb + (size_t)((c << 6) + j7) * NW;
      u64 oA = r0[lane] | r1[lane] | r2[lane] | r3[lane]
             | r4[lane] | r5[lane] | r6[lane] | r7[lane];
      u64 oB = 0;
      if (lane < 32)
        oB = r0[64 + lane] | r1[64 + lane] | r2[64 + lane] | r3[64 + lane]
           | r4[64 + lane] | r5[64 + lane] | r6[64 + lane] | r7[64 + lane];
      accA |= oA;
      accB |= oB;
    }
  }
}

// ---------------------------------------------------------------------------
extern "C" void kernel_launch(void* const* d_in, const int* in_sizes, int n_in,
                              void* d_out, int out_size, void* d_ws, size_t ws_size,
                              hipStream_t stream) {
  const float* x        = (const float*)d_in[0];
  const float* conv1_w  = (const float*)d_in[1];
  const float* conv1_b  = (const float*)d_in[2];
  const float* score_w  = (const float*)d_in[3];
  const float* score_b  = (const float*)d_in[4];
  const float* loc_w    = (const float*)d_in[5];
  const float* loc_b    = (const float*)d_in[6];
  const int*   imgh_p   = (const int*)d_in[7];
  const int*   imgw_p   = (const int*)d_in[8];

  float* out = (float*)d_out;
  float* ws  = (float*)d_ws;

  _Float16* xhi = (_Float16*)(ws + WS_XHI);
  _Float16* xlo = (_Float16*)(ws + WS_XLO);
  _Float16* whi = (_Float16*)(ws + WS_WHI);
  _Float16* wlo = (_Float16*)(ws + WS_WLO);
  float* wslt   = ws + WS_WSLT;
  float* wslb   = ws + WS_WSLB;
  float* hbuf   = ws + WS_H;
  float* guard  = ws + WS_GUARD;
  // overlays (xhi region is dead after conv)
  float* fgbuf   = ws + WS_FG;
  float4* roibuf = (float4*)(ws + WS_ROI);
  u64* keys      = (u64*)(ws + WS_KEYS);
  float4* sbox   = (float4*)(ws + WS_SBOX);
  u64* alive     = (u64*)(ws + WS_ALIVE);
  u64* maskbuf   = (u64*)(ws + WS_MASK);   // overlays whi/wlo (dead after conv)

  prep_all<<<5826, 256, 0, stream>>>(x, conv1_w, loc_w, score_w, loc_b, score_b,
                                     (float4*)hbuf, (float4*)guard,
                                     xhi, xlo, whi, wlo, wslt, wslb);

  conv_mfma<<<dim3(64, 4, 2), 256, 0, stream>>>(xhi, xlo, whi, wlo, guard, hbuf);

  head_kernel<<<dim3(64, 2), 256, 0, stream>>>(hbuf, conv1_b, wslt, wslb, out, fgbuf);
  decode_kernel<<<512, 256, 0, stream>>>(out, fgbuf, roibuf, keys,
                                         out + O4, out, imgh_p, imgw_p);

  sort_local_a<<<32, 256, 0, stream>>>(keys);
  for (int k = 8192; k <= SEG; k <<= 1) {
    int j = k >> 1;
    while (j >= 4096) {
      if (j >= 8192) {
        sort_global_pass2<<<128, 256, 0, stream>>>(keys, k, j);
        j >>= 2;
      } else {
        sort_global_pass<<<256, 256, 0, stream>>>(keys, k, j);
        j >>= 1;
      }
    }
    sort_local_b<<<32, 256, 0, stream>>>(keys, k);
  }

  nms_gather<<<dim3(24, 2), 256, 0, stream>>>(keys, roibuf, sbox, alive);
  build_mask<<<dim3(96, 4, 2), 256, 0, stream>>>(sbox, maskbuf);
  nms_reduce<<<2, 64, 0, stream>>>(maskbuf, alive, sbox, out);
}

// Round 4
// 500.100 us; speedup vs baseline: 1.1803x; 1.0879x over previous
//
#include <hip/hip_runtime.h>
#include <hip/hip_bf16.h>
#include <math.h>
#include <cstdint>

typedef unsigned long long u64;
typedef unsigned int u32;
typedef _Float16 half8 __attribute__((ext_vector_type(8)));
typedef float floatx4 __attribute__((ext_vector_type(4)));

// ---------------------------------------------------------------------------
// Sizes
// ---------------------------------------------------------------------------
#define NANCH 36864        // 4096*9
#define SEG 65536          // per-image key segment stride (layout only)
#define N_PRE 6000
#define N_POST 300
#define NW 96              // mask words per row (6144 bits)
#define NPADC 6144         // padded candidate count
#define CAP 8192           // compaction buffer capacity per image

// output float offsets
#define O0 0               // rpn_locs  2*36864*4 = 294912
#define O1 294912          // rpn_scores 2*36864*2 = 147456
#define O2 442368          // rois 2*300*4 = 2400
#define O3 444768          // roi_indices 600
#define O4 445368          // anchor 147456
#define O5 592824          // vmask 600

// workspace float offsets
#define WS_XHI   0                        // xhi f16 [2][4096][512] (2,097,152 f)
#define WS_XLO   2097152
#define WS_WHI   4194304                  // whi f16 [9][512][512] (1,179,648 f)
#define WS_WLO   5373952
#define WS_WSLT  6553600                  // 32768
#define WS_WSLB  6586368                  // 64
#define WS_H     6586432                  // hbuf f32 [2][4096][512] = 4,194,304 f
#define WS_GUARD 10780736                 // 64 floats of zeros (OOB target)
// overlays into dead XHI region (used only after conv completes):
#define WS_FG    0                        // 73728
#define WS_ROI   73728                    // 294912 (16B aligned)
#define WS_KEYS  368640                   // 131072 u64 = 262144 f
#define WS_SBOX  630784                   // 2*6144 float4 = 49152 f
#define WS_ALIVE 679936                   // 2*96 u64 = 384 f
#define WS_CBUF  680320                   // 2*8192 u64 = 32768 f
#define WS_HIST  713088                   // 2*65536 u32 = 131072 f
#define WS_CNT   844160                   // counters [0..1]=cnt, [2..3]=T
// overlay into dead WHI+WLO region (after conv): FULL suppression matrix
#define WS_MASK  4194304                  // 2*6144*96 u64 = 9,437,184 B (exact fit)

#define HSCALE 9.5367431640625e-07f       // 2^-20

// ---------------------------------------------------------------------------
__device__ __forceinline__ void gl_lds16(const void* g, void* l) {
  __builtin_amdgcn_global_load_lds(
      (const __attribute__((address_space(1))) u32*)g,
      (__attribute__((address_space(3))) u32*)l, 16, 0, 0);
}

__device__ __forceinline__ u64 bcast64(u64 v, int src) {
  u32 lo = (u32)__shfl((int)(v & 0xFFFFFFFFull), src);
  u32 hi = (u32)__shfl((int)(v >> 32), src);
  return ((u64)hi << 32) | lo;
}

// ---------------------------------------------------------------------------
// 0. fused prep: zero hbuf+guard | xcvt | wcvt | head-weight pack.
// ---------------------------------------------------------------------------
__global__ __launch_bounds__(256) void prep_all(
    const float* __restrict__ x, const float* __restrict__ w,
    const float* __restrict__ lw, const float* __restrict__ sw,
    const float* __restrict__ lb, const float* __restrict__ sb,
    float4* __restrict__ h, float4* __restrict__ guard,
    _Float16* __restrict__ xhi, _Float16* __restrict__ xlo,
    _Float16* __restrict__ whi, _Float16* __restrict__ wlo,
    float* __restrict__ wslt, float* __restrict__ wslb) {
  __shared__ float s[64 * 65];
  const int b = blockIdx.x, tid = threadIdx.x;
  if (b < 4097) {
    int idx = b * 256 + tid;
    if (idx < 1048576) h[idx] = make_float4(0.f, 0.f, 0.f, 0.f);
    else if (idx < 1048576 + 16) guard[idx - 1048576] = make_float4(0.f, 0.f, 0.f, 0.f);
    return;
  }
  if (b < 5121) {  // xcvt: [n][c][pix] f32 -> [n][pix][c] f16 hi/lo x1024
    int l = b - 4097;
    int pt = l & 63, cg = (l >> 6) & 7, n = l >> 9;
    const int c0 = cg << 6, p0 = pt << 6;
#pragma unroll
    for (int kk = 0; kk < 16; ++kk) {
      int e = tid + (kk << 8);
      int ci = e >> 6, pi = e & 63;
      s[ci * 65 + pi] = x[(((size_t)(n * 512 + c0 + ci)) << 12) + p0 + pi];
    }
    __syncthreads();
#pragma unroll
    for (int kk = 0; kk < 16; ++kk) {
      int e = tid + (kk << 8);
      int ci = e & 63, pi = e >> 6;
      float sv = s[ci * 65 + pi] * 1024.f;
      _Float16 hi = (_Float16)sv;
      _Float16 lo = (_Float16)(sv - (float)hi);
      size_t off = (((size_t)(n << 12) + p0 + pi) << 9) + c0 + ci;
      xhi[off] = hi;
      xlo[off] = lo;
    }
    return;
  }
  if (b < 5697) {  // wcvt: [o][c][3][3] -> [t][o][c] f16 hi/lo x1024
    int l = b - 5121;
    int ct = l & 7, ot = (l >> 3) & 7, t = l >> 6;
    const int c0 = ct << 6, o0 = ot << 6;
#pragma unroll
    for (int kk = 0; kk < 16; ++kk) {
      int e = tid + (kk << 8);
      int ci = e & 63, oi = e >> 6;
      float sv = w[(size_t)(o0 + oi) * 4608 + (c0 + ci) * 9 + t] * 1024.f;
      _Float16 hi = (_Float16)sv;
      _Float16 lo = (_Float16)(sv - (float)hi);
      size_t off = ((size_t)((t << 9) + o0 + oi) << 9) + c0 + ci;
      whi[off] = hi;
      wlo[off] = lo;
    }
    return;
  }
  {  // prep_small
    int e = (b - 5697) * 256 + tid;
    if (e < 32768) {
      int c = e >> 6, o = e & 63;
      float v = 0.f;
      if (o < 36) v = lw[o * 512 + c];
      else if (o < 54) v = sw[(o - 36) * 512 + c];
      wslt[e] = v;
    } else if (e < 32832) {
      int o = e - 32768;
      float v = 0.f;
      if (o < 36) v = lb[o];
      else if (o < 54) v = sb[o - 36];
      wslb[o] = v;
    }
  }
}

// ---------------------------------------------------------------------------
// 1. MFMA implicit-GEMM 3x3 conv (fp16x2 split: hh + hl + lh, fp32 acc).
// R0 structure restored verbatim: LDS DMA staging for BOTH A and B,
// __syncthreads per tap. Measured 121us = ~960 TF effective on the 3-pass
// GEMM (2MNK*3 = 1.16e11 FLOP) — at the known plain-HIP 2-barrier-structure
// ceiling (m97/m103 ~900-960 TF). Structural perturbations all regressed:
// R1 +pipelined dbuf 129us | R2 pass-split 217us | R3 B-in-regs 169us
// (register budget evicted the B double-buffer -> per-tap L2 latency).
// Do not touch without adopting a full 8-phase 256^2 schedule (which this
// problem's N=512 can't tile without starving CUs).
// ---------------------------------------------------------------------------
__global__ __launch_bounds__(256) void conv_mfma(
    const _Float16* __restrict__ xhi, const _Float16* __restrict__ xlo,
    const _Float16* __restrict__ whi, const _Float16* __restrict__ wlo,
    const float* __restrict__ guard, float* __restrict__ hout) {
  __shared__ _Float16 aHi[4 * 68 * 32];
  __shared__ _Float16 aLo[4 * 68 * 32];
  __shared__ _Float16 bHi[128 * 32];
  __shared__ _Float16 bLo[128 * 32];
  const int tid = threadIdx.x;
  const int lane = tid & 63, w = tid >> 6;
  const int ptile = blockIdx.x;
  const int og = blockIdx.y;
  const int kq = blockIdx.z;
  const int n = ptile >> 5;
  const int y0 = (ptile & 31) << 1;
  const int o0 = og << 7;
  const int l15 = lane & 15, l16 = lane >> 4;
  const int ry = w >> 1;
  const int wo = (w & 1) << 6;

  floatx4 acc[4][4];
#pragma unroll
  for (int a = 0; a < 4; ++a)
#pragma unroll
    for (int b = 0; b < 4; ++b) acc[a][b] = (floatx4)0.f;

  for (int s = 0; s < 8; ++s) {
    const int c0 = (kq << 8) + (s << 5);
    __syncthreads();
    for (int i = w; i < 17; i += 4) {
      int chunk = (i << 6) + lane;
      int p = chunk >> 2, q = chunk & 3;
      int r = p / 68, xs = p - r * 68;
      int y = y0 - 1 + r, xg = xs - 1;
      bool ok = ((unsigned)y < 64u) && ((unsigned)xg < 64u);
      size_t off = (((size_t)(n << 12) + (y << 6) + xg) << 9) + c0 + (q << 3);
      const void* gh = ok ? (const void*)(xhi + off) : (const void*)guard;
      const void* gl = ok ? (const void*)(xlo + off) : (const void*)guard;
      gl_lds16(gh, (char*)aHi + (i << 10));
      gl_lds16(gl, (char*)aLo + (i << 10));
    }
    for (int tt = 0; tt < 9; ++tt) {
      if (tt > 0) __syncthreads();
      for (int i = w; i < 8; i += 4) {
        int chunk = (i << 6) + lane;
        int row = chunk >> 2, q = chunk & 3;
        size_t off = ((size_t)((tt << 9) + o0 + row) << 9) + c0 + (q << 3);
        gl_lds16((const void*)(whi + off), (char*)bHi + (i << 10));
        gl_lds16((const void*)(wlo + off), (char*)bLo + (i << 10));
      }
      __syncthreads();

      const int dy = tt / 3, dx = tt - 3 * dy;
      half8 ah[4], al[4], bh[4], bl[4];
#pragma unroll
      for (int im = 0; im < 4; ++im) {
        int xp = (im << 4) + l15;
        int p = (ry + dy) * 68 + xp + dx;
        ah[im] = *(const half8*)&aHi[(p << 5) + (l16 << 3)];
        al[im] = *(const half8*)&aLo[(p << 5) + (l16 << 3)];
      }
#pragma unroll
      for (int in = 0; in < 4; ++in) {
        int orow = wo + (in << 4) + l15;
        bh[in] = *(const half8*)&bHi[(orow << 5) + (l16 << 3)];
        bl[in] = *(const half8*)&bLo[(orow << 5) + (l16 << 3)];
      }
#pragma unroll
      for (int im = 0; im < 4; ++im)
#pragma unroll
        for (int in = 0; in < 4; ++in) {
          acc[im][in] = __builtin_amdgcn_mfma_f32_16x16x32_f16(
              ah[im], bh[in], acc[im][in], 0, 0, 0);
          acc[im][in] = __builtin_amdgcn_mfma_f32_16x16x32_f16(
              ah[im], bl[in], acc[im][in], 0, 0, 0);
          acc[im][in] = __builtin_amdgcn_mfma_f32_16x16x32_f16(
              al[im], bh[in], acc[im][in], 0, 0, 0);
        }
    }
  }

#pragma unroll
  for (int im = 0; im < 4; ++im)
#pragma unroll
    for (int in = 0; in < 4; ++in) {
      int o = o0 + wo + (in << 4) + l15;
#pragma unroll
      for (int reg = 0; reg < 4; ++reg) {
        int m_local = (ry << 6) + (im << 4) + (l16 << 2) + reg;
        size_t off = (((size_t)(n << 12) + (y0 << 6) + m_local) << 9) + o;
        atomicAdd(&hout[off], acc[im][in][reg]);
      }
    }
}

// ---------------------------------------------------------------------------
// 2. 1x1 heads + softmax. grid (64 y, 2 n), block 256.
// ---------------------------------------------------------------------------
__global__ __launch_bounds__(256) void head_kernel(
    const float* __restrict__ hbuf, const float* __restrict__ cb,
    const float* __restrict__ wslt, const float* __restrict__ wslb,
    float* __restrict__ out, float* __restrict__ fgbuf) {
  const int y = blockIdx.x, n = blockIdx.y;
  __shared__ float sH[16 * 65];
  __shared__ float sWt[1024];
  __shared__ float sOut[64 * 65];
  const int tid = threadIdx.x;
  const int x = tid & 63, og = tid >> 6;

  float acc[16];
#pragma unroll
  for (int j = 0; j < 16; ++j) acc[j] = 0.f;

  const float* hb = hbuf + (((size_t)(n << 12) + (y << 6)) << 9);

  for (int c0 = 0; c0 < 512; c0 += 16) {
    __syncthreads();
#pragma unroll
    for (int p = 0; p < 4; ++p) {
      int e = tid + (p << 8);
      {
        int cc = e & 15, xx = e >> 4;
        float raw = hb[((size_t)xx << 9) + c0 + cc];
        sH[cc * 65 + xx] = fmaxf(raw * HSCALE + cb[c0 + cc], 0.f);
      }
      {
        int cc = e >> 6, xx = e & 63;
        sWt[e] = wslt[((c0 + cc) << 6) + xx];
      }
    }
    __syncthreads();
#pragma unroll
    for (int cc = 0; cc < 16; ++cc) {
      float hv = sH[cc * 65 + x];
      const float4* wp = (const float4*)&sWt[(cc << 6) + (og << 4)];
      float4 w0 = wp[0], w1 = wp[1], w2 = wp[2], w3 = wp[3];
      acc[0]  = fmaf(hv, w0.x, acc[0]);  acc[1]  = fmaf(hv, w0.y, acc[1]);
      acc[2]  = fmaf(hv, w0.z, acc[2]);  acc[3]  = fmaf(hv, w0.w, acc[3]);
      acc[4]  = fmaf(hv, w1.x, acc[4]);  acc[5]  = fmaf(hv, w1.y, acc[5]);
      acc[6]  = fmaf(hv, w1.z, acc[6]);  acc[7]  = fmaf(hv, w1.w, acc[7]);
      acc[8]  = fmaf(hv, w2.x, acc[8]);  acc[9]  = fmaf(hv, w2.y, acc[9]);
      acc[10] = fmaf(hv, w2.z, acc[10]); acc[11] = fmaf(hv, w2.w, acc[11]);
      acc[12] = fmaf(hv, w3.x, acc[12]); acc[13] = fmaf(hv, w3.y, acc[13]);
      acc[14] = fmaf(hv, w3.z, acc[14]); acc[15] = fmaf(hv, w3.w, acc[15]);
    }
  }
  __syncthreads();
#pragma unroll
  for (int j = 0; j < 16; ++j) {
    int o = (og << 4) + j;
    sOut[o * 65 + x] = acc[j] + wslb[o];
  }
  __syncthreads();

  const int p0 = (n << 12) + (y << 6);
  float* locs = out + O0 + (size_t)p0 * 36;
  for (int e = tid; e < 2304; e += 256) {
    int xx = e / 36, o = e - xx * 36;
    locs[e] = sOut[o * 65 + xx];
  }
  float* scrs = out + O1 + (size_t)p0 * 18;
  for (int e = tid; e < 1152; e += 256) {
    int xx = e / 18, ss = e - xx * 18;
    scrs[e] = sOut[(36 + ss) * 65 + xx];
  }
  float* fg = fgbuf + n * NANCH + (y << 6) * 9;
  for (int e = tid; e < 576; e += 256) {
    int xx = e / 9, a = e - xx * 9;
    float s0 = sOut[(36 + 2 * a) * 65 + xx];
    float s1 = sOut[(36 + 2 * a + 1) * 65 + xx];
    fg[e] = 1.0f / (1.0f + expf(s0 - s1));
  }
}

// ---------------------------------------------------------------------------
// 3. anchors + decode + clip + min-size + sort keys. Also zero-inits the
// selection histogram / compaction buffers / counters (same thread count).
// ---------------------------------------------------------------------------
__global__ __launch_bounds__(256) void decode_kernel(
    const float* __restrict__ out0, const float* __restrict__ fgbuf,
    float4* __restrict__ roibuf, u64* __restrict__ keys,
    float* __restrict__ anchor_out, float* __restrict__ out,
    u32* __restrict__ hist, u64* __restrict__ cbuf, u32* __restrict__ cnt,
    const int* __restrict__ imgh_p, const int* __restrict__ imgw_p) {
  int gid = blockIdx.x * 256 + threadIdx.x;   // < 131072
  hist[gid] = 0u;                              // 2*65536 == grid exactly
  if (gid < 2 * CAP) cbuf[gid] = ~0ull;
  if (gid < 4) cnt[gid] = 0u;
  if (gid < 3600) {
    if (gid < 2400) out[O2 + gid] = 0.f;
    else if (gid < 3000) out[O3 + (gid - 2400)] = (float)((gid - 2400) / 300);
    else out[O5 + (gid - 3000)] = 0.f;
  }
  int n = gid >> 16, k = gid & (SEG - 1);
  if (k >= NANCH) return;
  int a = k % 9;
  int p = k / 9;
  int py = p >> 6, px = p & 63;

  const double R[3] = {0.5, 1.0, 2.0};
  const double S[3] = {8.0, 16.0, 32.0};
  double r = R[a / 3], s = S[a - (a / 3) * 3];
  double hd = 16.0 * s * sqrt(r);
  double wd = 16.0 * s * sqrt(1.0 / r);
  float ay1 = (float)(8.0 - hd / 2.0) + (float)(py * 16);
  float ax1 = (float)(8.0 - wd / 2.0) + (float)(px * 16);
  float ay2 = (float)(8.0 + hd / 2.0) + (float)(py * 16);
  float ax2 = (float)(8.0 + wd / 2.0) + (float)(px * 16);
  if (n == 0) {
    float* ao = anchor_out + (size_t)k * 4;
    ao[0] = ay1; ao[1] = ax1; ao[2] = ay2; ao[3] = ax2;
  }
  float ahk = ay2 - ay1, awk = ax2 - ax1;
  float acy = ay1 + 0.5f * ahk, acx = ax1 + 0.5f * awk;
  const float* lp = out0 + ((size_t)(n * NANCH + k) << 2);
  float dy = lp[0], dx = lp[1], dh = lp[2], dw = lp[3];
  float cy = dy * ahk + acy;
  float cx = dx * awk + acx;
  float bh = expf(dh) * ahk;
  float bw = expf(dw) * awk;
  float img_h = (float)imgh_p[0], img_w = (float)imgw_p[0];
  float y1 = fminf(fmaxf(cy - 0.5f * bh, 0.f), img_h);
  float x1 = fminf(fmaxf(cx - 0.5f * bw, 0.f), img_w);
  float y2 = fminf(fmaxf(cy + 0.5f * bh, 0.f), img_h);
  float x2 = fminf(fmaxf(cx + 0.5f * bw, 0.f), img_w);
  bool valid = ((y2 - y1) >= 16.f) && ((x2 - x1) >= 16.f);
  float sc = valid ? fgbuf[n * NANCH + k] : -INFINITY;
  roibuf[n * NANCH + k] = make_float4(y1, x1, y2, x2);
  unsigned int b = __float_as_uint(sc);
  unsigned int m = b ^ ((b & 0x80000000u) ? 0xFFFFFFFFu : 0x80000000u);
  keys[gid] = ((u64)(~m) << 32) | (unsigned int)k;
}

// ---------------------------------------------------------------------------
// 4. top-6000 selection (replaces the 11-launch bitonic sort chain).
// 4a. histogram of the 32-bit monotone score key, 65536 bins (top 16 bits).
// ---------------------------------------------------------------------------
__global__ __launch_bounds__(256) void hist_kernel(
    const u64* __restrict__ keys, u32* __restrict__ hist) {
  const int n = blockIdx.y;
  int i = blockIdx.x * 256 + threadIdx.x;            // < 36864
  u32 hk = (u32)(keys[(n << 16) + i] >> 32);
  if (hk < 0xFF800000u) atomicAdd(&hist[(n << 16) + (hk >> 16)], 1u);
}

// ---------------------------------------------------------------------------
// 4b. rank-6000 bin threshold. 1 block of 1024 per image; each thread sums
// 64 bins, block-scan, crossing thread pinpoints the bin. T written to
// cnt[2+n] (pre-zeroed; stays 0 when no valid keys -> nothing compacts).
// ---------------------------------------------------------------------------
__global__ __launch_bounds__(1024) void thresh_kernel(
    const u32* __restrict__ hist, u32* __restrict__ cnt) {
  const int n = blockIdx.x, t = threadIdx.x;
  __shared__ u32 sc[1024];
  const uint4* hp = (const uint4*)(hist + (n << 16));
  u32 s = 0;
#pragma unroll
  for (int q = 0; q < 16; ++q) {
    uint4 v = hp[t * 16 + q];
    s += v.x + v.y + v.z + v.w;
  }
  sc[t] = s;
  __syncthreads();
  for (int off = 1; off < 1024; off <<= 1) {
    u32 v = (t >= off) ? sc[t - off] : 0u;
    __syncthreads();
    sc[t] += v;
    __syncthreads();
  }
  u32 total = sc[1023];
  u32 target = total < (u32)N_PRE ? total : (u32)N_PRE;
  u32 mycum = sc[t];
  u32 prev = t ? sc[t - 1] : 0u;
  if (total > 0 && mycum >= target && prev < target) {
    u32 base = prev;
    int b = t << 6;
    while (true) {
      base += hist[(n << 16) + b];
      if (base >= target) break;
      ++b;
    }
    cnt[2 + n] = (u32)b;
  }
}

// ---------------------------------------------------------------------------
// 4c. compact all keys with bin <= T (<= ~6000 + one bin of ties < CAP).
// Unordered; the single-block sort after restores exact order.
// ---------------------------------------------------------------------------
__global__ __launch_bounds__(256) void compact_kernel(
    const u64* __restrict__ keys, u32* __restrict__ cnt,
    u64* __restrict__ cbuf) {
  const int n = blockIdx.y;
  int i = blockIdx.x * 256 + threadIdx.x;            // < 36864
  u64 key = keys[(n << 16) + i];
  u32 hk = (u32)(key >> 32);
  u32 T = cnt[2 + n];
  if (hk < 0xFF800000u && (hk >> 16) <= T) {
    u32 slot = atomicAdd(&cnt[n], 1u);
    if (slot < (u32)CAP) cbuf[(n << 13) + slot] = key;
  }
}

// ---------------------------------------------------------------------------
// 4d. single-block 8192-element bitonic sort per image, fused with the
// sbox/alive gather (replaces sort chain tail + nms_gather). Padding ~0ull
// sorts last and fails the validity check, matching old behavior.
// ---------------------------------------------------------------------------
__global__ __launch_bounds__(1024) void sortgather_kernel(
    const u64* __restrict__ cbuf, const float4* __restrict__ roibuf,
    float4* __restrict__ sbox, u64* __restrict__ alive) {
  __shared__ u64 sk[CAP];
  const int n = blockIdx.x, t = threadIdx.x;
  for (int e = t; e < CAP; e += 1024) sk[e] = cbuf[(n << 13) + e];
  __syncthreads();
  for (int k = 2; k <= CAP; k <<= 1) {
    for (int j = k >> 1; j > 0; j >>= 1) {
      for (int q = t; q < (CAP >> 1); q += 1024) {
        int l = ((q & ~(j - 1)) << 1) | (q & (j - 1));
        int rr = l | j;
        bool asc = ((l & k) == 0);
        u64 a = sk[l], b = sk[rr];
        if ((a > b) == asc) { sk[l] = b; sk[rr] = a; }
      }
      __syncthreads();
    }
  }
  for (int i = t; i < NPADC; i += 1024) {
    u64 kk = sk[i];
    bool valid = (i < N_PRE) && ((u32)(kk >> 32) < 0xFF800000u);
    float4 b = make_float4(0.f, 0.f, 0.f, 0.f);
    if (valid) b = roibuf[(size_t)n * NANCH + (u32)(kk & 0xFFFFFFFFull)];
    sbox[n * NPADC + i] = b;
    u64 bal = __ballot(valid);
    if ((t & 63) == 0) alive[n * NW + (i >> 6)] = bal;
  }
}

// ---------------------------------------------------------------------------
// 6b. build FULL suppression matrix (both triangles; symmetric).
// ---------------------------------------------------------------------------
__global__ __launch_bounds__(256) void build_mask(
    const float4* __restrict__ sbox, u64* __restrict__ M) {
  __shared__ float4 jb[4][64];
  __shared__ float ja[4][64];
  const int tid = threadIdx.x, lane = tid & 63, wv = tid >> 6;
  const int g = blockIdx.x, q = blockIdx.y, n = blockIdx.z;
  const float4* sb = sbox + n * NPADC;
  float4 bi = sb[(g << 6) + lane];
  float ai = (bi.z - bi.x) * (bi.w - bi.y);
  u64* Mrow = M + ((size_t)(n * NPADC + (g << 6) + lane)) * NW;
#pragma unroll
  for (int it = 0; it < 6; ++it) {
    int w = q * 24 + (it << 2) + wv;
    float4 bjl = sb[(w << 6) + lane];
    jb[wv][lane] = bjl;
    ja[wv][lane] = (bjl.z - bjl.x) * (bjl.w - bjl.y);
    u64 bits = 0;
#pragma unroll 8
    for (int j = 0; j < 64; ++j) {
      float4 bj = jb[wv][j];
      float aj = ja[wv][j];
      float ih = fmaxf(fminf(bi.z, bj.z) - fmaxf(bi.x, bj.x), 0.f);
      float iw = fmaxf(fminf(bi.w, bj.w) - fmaxf(bi.y, bj.y), 0.f);
      float inter = ih * iw;
      bool bit = inter / (ai + aj - inter + 1e-9f) > 0.7f;
      bits |= ((u64)bit) << j;
    }
    Mrow[w] = bits;
  }
}

// ---------------------------------------------------------------------------
// 6c. serial greedy reduce, one wave per image.
// ---------------------------------------------------------------------------
__global__ __launch_bounds__(64) void nms_reduce(
    const u64* __restrict__ M, const u64* __restrict__ alive,
    const float4* __restrict__ sbox, float* __restrict__ out) {
  const int n = blockIdx.x, lane = threadIdx.x;
  float* rois = out + O2 + n * (N_POST * 4);
  float* vmask = out + O5 + n * N_POST;
  const u64* A = alive + n * NW;
  const u64* Mb = M + (size_t)n * NPADC * NW;
  const float4* sb = sbox + n * NPADC;
  u64 aw0 = A[lane];
  u64 aw1 = (lane < 32) ? A[64 + lane] : 0ull;
  u64 accA = 0, accB = 0;
  int nk = 0;
  u64 dnext = Mb[(size_t)lane * NW + 0];
  float4 bnext = sb[lane];
  const u64 below = lane ? (~0ull >> (64 - lane)) : 0ull;

  for (int c = 0; c < 94; ++c) {
    u64 dcur = dnext;
    float4 bcur = bnext;
    if (c + 1 < 94) {
      dnext = Mb[(size_t)(((c + 1) << 6) + lane) * NW + (c + 1)];
      bnext = sb[((c + 1) << 6) + lane];
    }
    u64 wacc = (c < 64) ? bcast64(accA, c) : bcast64(accB, c - 64);
    u64 aw = (c < 64) ? bcast64(aw0, c) : bcast64(aw1, c - 64);
    u64 alive_u = aw & ~wacc;
    if (alive_u == 0ull) continue;

    u64 dmask = dcur & below;
    u64 rem = alive_u, kept = 0;
    while (rem) {
      int j = __builtin_ctzll(rem);
      kept |= 1ull << j;
      u64 col = __ballot((dmask >> j) & 1);
      rem &= ~(col | (1ull << j));
    }

    int npop = __popcll(kept);
    if ((kept >> lane) & 1ull) {
      int slot = nk + __popcll(kept & below);
      if (slot < N_POST) {
        rois[slot * 4 + 0] = bcur.x; rois[slot * 4 + 1] = bcur.y;
        rois[slot * 4 + 2] = bcur.z; rois[slot * 4 + 3] = bcur.w;
        vmask[slot] = 1.0f;
      }
    }
    if (nk + npop >= N_POST) break;
    nk += npop;

    u64 kk = kept;
    while (kk) {
      int j0 = __builtin_ctzll(kk); kk &= kk - 1;
      int j1 = kk ? __builtin_ctzll(kk) : j0; kk &= kk - 1;
      int j2 = kk ? __builtin_ctzll(kk) : j0; kk &= kk - 1;
      int j3 = kk ? __builtin_ctzll(kk) : j0; kk &= kk - 1;
      int j4 = kk ? __builtin_ctzll(kk) : j0; kk &= kk - 1;
      int j5 = kk ? __builtin_ctzll(kk) : j0; kk &= kk - 1;
      int j6 = kk ? __builtin_ctzll(kk) : j0; kk &= kk - 1;
      int j7 = kk ? __builtin_ctzll(kk) : j0; kk &= kk - 1;
      const u64* r0 = Mb + (size_t)((c << 6) + j0) * NW;
      const u64* r1 = Mb + (size_t)((c << 6) + j1) * NW;
      const u64* r2 = Mb + (size_t)((c << 6) + j2) * NW;
      const u64* r3 = Mb + (size_t)((c << 6) + j3) * NW;
      const u64* r4 = Mb + (size_t)((c << 6) + j4) * NW;
      const u64* r5 = Mb + (size_t)((c << 6) + j5) * NW;
      const u64* r6 = Mb + (size_t)((c << 6) + j6) * NW;
      const u64* r7 = Mb + (size_t)((c << 6) + j7) * NW;
      u64 oA = r0[lane] | r1[lane] | r2[lane] | r3[lane]
             | r4[lane] | r5[lane] | r6[lane] | r7[lane];
      u64 oB = 0;
      if (lane < 32)
        oB = r0[64 + lane] | r1[64 + lane] | r2[64 + lane] | r3[64 + lane]
           | r4[64 + lane] | r5[64 + lane] | r6[64 + lane] | r7[64 + lane];
      accA |= oA;
      accB |= oB;
    }
  }
}

// ---------------------------------------------------------------------------
extern "C" void kernel_launch(void* const* d_in, const int* in_sizes, int n_in,
                              void* d_out, int out_size, void* d_ws, size_t ws_size,
                              hipStream_t stream) {
  const float* x        = (const float*)d_in[0];
  const float* conv1_w  = (const float*)d_in[1];
  const float* conv1_b  = (const float*)d_in[2];
  const float* score_w  = (const float*)d_in[3];
  const float* score_b  = (const float*)d_in[4];
  const float* loc_w    = (const float*)d_in[5];
  const float* loc_b    = (const float*)d_in[6];
  const int*   imgh_p   = (const int*)d_in[7];
  const int*   imgw_p   = (const int*)d_in[8];

  float* out = (float*)d_out;
  float* ws  = (float*)d_ws;

  _Float16* xhi = (_Float16*)(ws + WS_XHI);
  _Float16* xlo = (_Float16*)(ws + WS_XLO);
  _Float16* whi = (_Float16*)(ws + WS_WHI);
  _Float16* wlo = (_Float16*)(ws + WS_WLO);
  float* wslt   = ws + WS_WSLT;
  float* wslb   = ws + WS_WSLB;
  float* hbuf   = ws + WS_H;
  float* guard  = ws + WS_GUARD;
  // overlays (xhi region is dead after conv)
  float* fgbuf   = ws + WS_FG;
  float4* roibuf = (float4*)(ws + WS_ROI);
  u64* keys      = (u64*)(ws + WS_KEYS);
  float4* sbox   = (float4*)(ws + WS_SBOX);
  u64* alive     = (u64*)(ws + WS_ALIVE);
  u64* cbuf      = (u64*)(ws + WS_CBUF);
  u32* hist      = (u32*)(ws + WS_HIST);
  u32* cnt       = (u32*)(ws + WS_CNT);
  u64* maskbuf   = (u64*)(ws + WS_MASK);   // overlays whi/wlo (dead after conv)

  prep_all<<<5826, 256, 0, stream>>>(x, conv1_w, loc_w, score_w, loc_b, score_b,
                                     (float4*)hbuf, (float4*)guard,
                                     xhi, xlo, whi, wlo, wslt, wslb);

  conv_mfma<<<dim3(64, 4, 2), 256, 0, stream>>>(xhi, xlo, whi, wlo, guard, hbuf);

  head_kernel<<<dim3(64, 2), 256, 0, stream>>>(hbuf, conv1_b, wslt, wslb, out, fgbuf);
  decode_kernel<<<512, 256, 0, stream>>>(out, fgbuf, roibuf, keys,
                                         out + O4, out, hist, cbuf, cnt,
                                         imgh_p, imgw_p);

  hist_kernel<<<dim3(144, 2), 256, 0, stream>>>(keys, hist);
  thresh_kernel<<<2, 1024, 0, stream>>>(hist, cnt);
  compact_kernel<<<dim3(144, 2), 256, 0, stream>>>(keys, cnt, cbuf);
  sortgather_kernel<<<2, 1024, 0, stream>>>(cbuf, roibuf, sbox, alive);

  build_mask<<<dim3(96, 4, 2), 256, 0, stream>>>(sbox, maskbuf);
  nms_reduce<<<2, 64, 0, stream>>>(maskbuf, alive, sbox, out);
}

// Round 5
// 495.320 us; speedup vs baseline: 1.1917x; 1.0096x over previous
//
#include <hip/hip_runtime.h>
#include <hip/hip_bf16.h>
#include <math.h>
#include <cstdint>

typedef unsigned long long u64;
typedef unsigned int u32;
typedef _Float16 half8 __attribute__((ext_vector_type(8)));
typedef float floatx4 __attribute__((ext_vector_type(4)));

// ---------------------------------------------------------------------------
// Sizes
// ---------------------------------------------------------------------------
#define NANCH 36864        // 4096*9
#define SEG 65536          // per-image key segment stride (layout only)
#define N_PRE 6000
#define N_POST 300
#define NW 96              // mask words per row (6144 bits)
#define NPADC 6144         // padded candidate count
#define CAP 8192           // compaction buffer capacity per image

// output float offsets
#define O0 0               // rpn_locs  2*36864*4 = 294912
#define O1 294912          // rpn_scores 2*36864*2 = 147456
#define O2 442368          // rois 2*300*4 = 2400
#define O3 444768          // roi_indices 600
#define O4 445368          // anchor 147456
#define O5 592824          // vmask 600

// workspace float offsets
#define WS_XHI   0                        // xhi f16 [2][4096][512] (2,097,152 f)
#define WS_XLO   2097152
#define WS_WHI   4194304                  // whi f16 [9][512][512] (1,179,648 f)
#define WS_WLO   5373952
#define WS_WSLT  6553600                  // 32768
#define WS_WSLB  6586368                  // 64
#define WS_H     6586432                  // hbuf f32 [2][4096][512] = 4,194,304 f
#define WS_GUARD 10780736                 // 64 floats of zeros (OOB target)
// overlays into dead XHI region (used only after conv completes):
#define WS_FG    0                        // 73728
#define WS_ROI   73728                    // 294912 (16B aligned)
#define WS_KEYS  368640                   // 131072 u64 = 262144 f
#define WS_SBOX  630784                   // 2*6144 float4 = 49152 f
#define WS_ALIVE 679936                   // 2*96 u64 = 384 f
#define WS_CBUF  680320                   // (unused after R5 fusion; kept for layout)
#define WS_HIST  713088                   // 2*65536 u32 = 131072 f
// overlay into dead WHI+WLO region (after conv): FULL suppression matrix
#define WS_MASK  4194304                  // 2*6144*96 u64 = 9,437,184 B (exact fit)

#define HSCALE 9.5367431640625e-07f       // 2^-20

// ---------------------------------------------------------------------------
__device__ __forceinline__ void gl_lds16(const void* g, void* l) {
  __builtin_amdgcn_global_load_lds(
      (const __attribute__((address_space(1))) u32*)g,
      (__attribute__((address_space(3))) u32*)l, 16, 0, 0);
}

__device__ __forceinline__ u64 bcast64(u64 v, int src) {
  u32 lo = (u32)__shfl((int)(v & 0xFFFFFFFFull), src);
  u32 hi = (u32)__shfl((int)(v >> 32), src);
  return ((u64)hi << 32) | lo;
}

// ---------------------------------------------------------------------------
// 0. fused prep: zero hbuf+guard | xcvt | wcvt | head-weight pack.
// ---------------------------------------------------------------------------
__global__ __launch_bounds__(256) void prep_all(
    const float* __restrict__ x, const float* __restrict__ w,
    const float* __restrict__ lw, const float* __restrict__ sw,
    const float* __restrict__ lb, const float* __restrict__ sb,
    float4* __restrict__ h, float4* __restrict__ guard,
    _Float16* __restrict__ xhi, _Float16* __restrict__ xlo,
    _Float16* __restrict__ whi, _Float16* __restrict__ wlo,
    float* __restrict__ wslt, float* __restrict__ wslb) {
  __shared__ float s[64 * 65];
  const int b = blockIdx.x, tid = threadIdx.x;
  if (b < 4097) {
    int idx = b * 256 + tid;
    if (idx < 1048576) h[idx] = make_float4(0.f, 0.f, 0.f, 0.f);
    else if (idx < 1048576 + 16) guard[idx - 1048576] = make_float4(0.f, 0.f, 0.f, 0.f);
    return;
  }
  if (b < 5121) {  // xcvt: [n][c][pix] f32 -> [n][pix][c] f16 hi/lo x1024
    int l = b - 4097;
    int pt = l & 63, cg = (l >> 6) & 7, n = l >> 9;
    const int c0 = cg << 6, p0 = pt << 6;
#pragma unroll
    for (int kk = 0; kk < 16; ++kk) {
      int e = tid + (kk << 8);
      int ci = e >> 6, pi = e & 63;
      s[ci * 65 + pi] = x[(((size_t)(n * 512 + c0 + ci)) << 12) + p0 + pi];
    }
    __syncthreads();
#pragma unroll
    for (int kk = 0; kk < 16; ++kk) {
      int e = tid + (kk << 8);
      int ci = e & 63, pi = e >> 6;
      float sv = s[ci * 65 + pi] * 1024.f;
      _Float16 hi = (_Float16)sv;
      _Float16 lo = (_Float16)(sv - (float)hi);
      size_t off = (((size_t)(n << 12) + p0 + pi) << 9) + c0 + ci;
      xhi[off] = hi;
      xlo[off] = lo;
    }
    return;
  }
  if (b < 5697) {  // wcvt: [o][c][3][3] -> [t][o][c] f16 hi/lo x1024
    int l = b - 5121;
    int ct = l & 7, ot = (l >> 3) & 7, t = l >> 6;
    const int c0 = ct << 6, o0 = ot << 6;
#pragma unroll
    for (int kk = 0; kk < 16; ++kk) {
      int e = tid + (kk << 8);
      int ci = e & 63, oi = e >> 6;
      float sv = w[(size_t)(o0 + oi) * 4608 + (c0 + ci) * 9 + t] * 1024.f;
      _Float16 hi = (_Float16)sv;
      _Float16 lo = (_Float16)(sv - (float)hi);
      size_t off = ((size_t)((t << 9) + o0 + oi) << 9) + c0 + ci;
      whi[off] = hi;
      wlo[off] = lo;
    }
    return;
  }
  {  // prep_small
    int e = (b - 5697) * 256 + tid;
    if (e < 32768) {
      int c = e >> 6, o = e & 63;
      float v = 0.f;
      if (o < 36) v = lw[o * 512 + c];
      else if (o < 54) v = sw[(o - 36) * 512 + c];
      wslt[e] = v;
    } else if (e < 32832) {
      int o = e - 32768;
      float v = 0.f;
      if (o < 36) v = lb[o];
      else if (o < 54) v = sb[o - 36];
      wslb[o] = v;
    }
  }
}

// ---------------------------------------------------------------------------
// 1. MFMA implicit-GEMM 3x3 conv (fp16x2 split: hh + hl + lh, fp32 acc).
// R0 structure, parked: 121us = ~960 TF effective on the 3-pass GEMM —
// at the plain-HIP 2-barrier-structure ceiling (m97/m103). Perturbations
// all regressed: R1 pipelined dbuf 129 | R2 pass-split 217 | R3 B-in-regs
// 169 (VGPR budget evicted the B double-buffer -> per-tap L2 latency).
// Do not touch.
// ---------------------------------------------------------------------------
__global__ __launch_bounds__(256) void conv_mfma(
    const _Float16* __restrict__ xhi, const _Float16* __restrict__ xlo,
    const _Float16* __restrict__ whi, const _Float16* __restrict__ wlo,
    const float* __restrict__ guard, float* __restrict__ hout) {
  __shared__ _Float16 aHi[4 * 68 * 32];
  __shared__ _Float16 aLo[4 * 68 * 32];
  __shared__ _Float16 bHi[128 * 32];
  __shared__ _Float16 bLo[128 * 32];
  const int tid = threadIdx.x;
  const int lane = tid & 63, w = tid >> 6;
  const int ptile = blockIdx.x;
  const int og = blockIdx.y;
  const int kq = blockIdx.z;
  const int n = ptile >> 5;
  const int y0 = (ptile & 31) << 1;
  const int o0 = og << 7;
  const int l15 = lane & 15, l16 = lane >> 4;
  const int ry = w >> 1;
  const int wo = (w & 1) << 6;

  floatx4 acc[4][4];
#pragma unroll
  for (int a = 0; a < 4; ++a)
#pragma unroll
    for (int b = 0; b < 4; ++b) acc[a][b] = (floatx4)0.f;

  for (int s = 0; s < 8; ++s) {
    const int c0 = (kq << 8) + (s << 5);
    __syncthreads();
    for (int i = w; i < 17; i += 4) {
      int chunk = (i << 6) + lane;
      int p = chunk >> 2, q = chunk & 3;
      int r = p / 68, xs = p - r * 68;
      int y = y0 - 1 + r, xg = xs - 1;
      bool ok = ((unsigned)y < 64u) && ((unsigned)xg < 64u);
      size_t off = (((size_t)(n << 12) + (y << 6) + xg) << 9) + c0 + (q << 3);
      const void* gh = ok ? (const void*)(xhi + off) : (const void*)guard;
      const void* gl = ok ? (const void*)(xlo + off) : (const void*)guard;
      gl_lds16(gh, (char*)aHi + (i << 10));
      gl_lds16(gl, (char*)aLo + (i << 10));
    }
    for (int tt = 0; tt < 9; ++tt) {
      if (tt > 0) __syncthreads();
      for (int i = w; i < 8; i += 4) {
        int chunk = (i << 6) + lane;
        int row = chunk >> 2, q = chunk & 3;
        size_t off = ((size_t)((tt << 9) + o0 + row) << 9) + c0 + (q << 3);
        gl_lds16((const void*)(whi + off), (char*)bHi + (i << 10));
        gl_lds16((const void*)(wlo + off), (char*)bLo + (i << 10));
      }
      __syncthreads();

      const int dy = tt / 3, dx = tt - 3 * dy;
      half8 ah[4], al[4], bh[4], bl[4];
#pragma unroll
      for (int im = 0; im < 4; ++im) {
        int xp = (im << 4) + l15;
        int p = (ry + dy) * 68 + xp + dx;
        ah[im] = *(const half8*)&aHi[(p << 5) + (l16 << 3)];
        al[im] = *(const half8*)&aLo[(p << 5) + (l16 << 3)];
      }
#pragma unroll
      for (int in = 0; in < 4; ++in) {
        int orow = wo + (in << 4) + l15;
        bh[in] = *(const half8*)&bHi[(orow << 5) + (l16 << 3)];
        bl[in] = *(const half8*)&bLo[(orow << 5) + (l16 << 3)];
      }
#pragma unroll
      for (int im = 0; im < 4; ++im)
#pragma unroll
        for (int in = 0; in < 4; ++in) {
          acc[im][in] = __builtin_amdgcn_mfma_f32_16x16x32_f16(
              ah[im], bh[in], acc[im][in], 0, 0, 0);
          acc[im][in] = __builtin_amdgcn_mfma_f32_16x16x32_f16(
              ah[im], bl[in], acc[im][in], 0, 0, 0);
          acc[im][in] = __builtin_amdgcn_mfma_f32_16x16x32_f16(
              al[im], bh[in], acc[im][in], 0, 0, 0);
        }
    }
  }

#pragma unroll
  for (int im = 0; im < 4; ++im)
#pragma unroll
    for (int in = 0; in < 4; ++in) {
      int o = o0 + wo + (in << 4) + l15;
#pragma unroll
      for (int reg = 0; reg < 4; ++reg) {
        int m_local = (ry << 6) + (im << 4) + (l16 << 2) + reg;
        size_t off = (((size_t)(n << 12) + (y0 << 6) + m_local) << 9) + o;
        atomicAdd(&hout[off], acc[im][in][reg]);
      }
    }
}

// ---------------------------------------------------------------------------
// 2. 1x1 heads + softmax. grid (64 y, 2 n), block 256.
// R5: also zero-inits hist (selection histogram) — must complete before
// decode_kernel's fused histogram atomics (stream order guarantees it).
// ---------------------------------------------------------------------------
__global__ __launch_bounds__(256) void head_kernel(
    const float* __restrict__ hbuf, const float* __restrict__ cb,
    const float* __restrict__ wslt, const float* __restrict__ wslb,
    float* __restrict__ out, float* __restrict__ fgbuf,
    uint4* __restrict__ hist4) {
  const int y = blockIdx.x, n = blockIdx.y;
  __shared__ float sH[16 * 65];
  __shared__ float sWt[1024];
  __shared__ float sOut[64 * 65];
  const int tid = threadIdx.x;
  const int x = tid & 63, og = tid >> 6;

  // init for the selection path (128 blocks x 256 = 32768 lanes)
  {
    int gid = ((n << 6) + y) * 256 + tid;          // 0..32767
    hist4[gid] = make_uint4(0u, 0u, 0u, 0u);       // 32768*16B = 512 KB = hist
  }

  float acc[16];
#pragma unroll
  for (int j = 0; j < 16; ++j) acc[j] = 0.f;

  const float* hb = hbuf + (((size_t)(n << 12) + (y << 6)) << 9);

  for (int c0 = 0; c0 < 512; c0 += 16) {
    __syncthreads();
#pragma unroll
    for (int p = 0; p < 4; ++p) {
      int e = tid + (p << 8);
      {
        int cc = e & 15, xx = e >> 4;
        float raw = hb[((size_t)xx << 9) + c0 + cc];
        sH[cc * 65 + xx] = fmaxf(raw * HSCALE + cb[c0 + cc], 0.f);
      }
      {
        int cc = e >> 6, xx = e & 63;
        sWt[e] = wslt[((c0 + cc) << 6) + xx];
      }
    }
    __syncthreads();
#pragma unroll
    for (int cc = 0; cc < 16; ++cc) {
      float hv = sH[cc * 65 + x];
      const float4* wp = (const float4*)&sWt[(cc << 6) + (og << 4)];
      float4 w0 = wp[0], w1 = wp[1], w2 = wp[2], w3 = wp[3];
      acc[0]  = fmaf(hv, w0.x, acc[0]);  acc[1]  = fmaf(hv, w0.y, acc[1]);
      acc[2]  = fmaf(hv, w0.z, acc[2]);  acc[3]  = fmaf(hv, w0.w, acc[3]);
      acc[4]  = fmaf(hv, w1.x, acc[4]);  acc[5]  = fmaf(hv, w1.y, acc[5]);
      acc[6]  = fmaf(hv, w1.z, acc[6]);  acc[7]  = fmaf(hv, w1.w, acc[7]);
      acc[8]  = fmaf(hv, w2.x, acc[8]);  acc[9]  = fmaf(hv, w2.y, acc[9]);
      acc[10] = fmaf(hv, w2.z, acc[10]); acc[11] = fmaf(hv, w2.w, acc[11]);
      acc[12] = fmaf(hv, w3.x, acc[12]); acc[13] = fmaf(hv, w3.y, acc[13]);
      acc[14] = fmaf(hv, w3.z, acc[14]); acc[15] = fmaf(hv, w3.w, acc[15]);
    }
  }
  __syncthreads();
#pragma unroll
  for (int j = 0; j < 16; ++j) {
    int o = (og << 4) + j;
    sOut[o * 65 + x] = acc[j] + wslb[o];
  }
  __syncthreads();

  const int p0 = (n << 12) + (y << 6);
  float* locs = out + O0 + (size_t)p0 * 36;
  for (int e = tid; e < 2304; e += 256) {
    int xx = e / 36, o = e - xx * 36;
    locs[e] = sOut[o * 65 + xx];
  }
  float* scrs = out + O1 + (size_t)p0 * 18;
  for (int e = tid; e < 1152; e += 256) {
    int xx = e / 18, ss = e - xx * 18;
    scrs[e] = sOut[(36 + ss) * 65 + xx];
  }
  float* fg = fgbuf + n * NANCH + (y << 6) * 9;
  for (int e = tid; e < 576; e += 256) {
    int xx = e / 9, a = e - xx * 9;
    float s0 = sOut[(36 + 2 * a) * 65 + xx];
    float s1 = sOut[(36 + 2 * a + 1) * 65 + xx];
    fg[e] = 1.0f / (1.0f + expf(s0 - s1));
  }
}

// ---------------------------------------------------------------------------
// 3. anchors + decode + clip + min-size + sort keys + FUSED histogram
// (R5: hist_kernel folded in — same thread domain; hist pre-zeroed by head).
// ---------------------------------------------------------------------------
__global__ __launch_bounds__(256) void decode_kernel(
    const float* __restrict__ out0, const float* __restrict__ fgbuf,
    float4* __restrict__ roibuf, u64* __restrict__ keys,
    float* __restrict__ anchor_out, float* __restrict__ out,
    u32* __restrict__ hist,
    const int* __restrict__ imgh_p, const int* __restrict__ imgw_p) {
  int gid = blockIdx.x * 256 + threadIdx.x;   // < 131072
  if (gid < 3600) {
    if (gid < 2400) out[O2 + gid] = 0.f;
    else if (gid < 3000) out[O3 + (gid - 2400)] = (float)((gid - 2400) / 300);
    else out[O5 + (gid - 3000)] = 0.f;
  }
  int n = gid >> 16, k = gid & (SEG - 1);
  if (k >= NANCH) return;
  int a = k % 9;
  int p = k / 9;
  int py = p >> 6, px = p & 63;

  const double R[3] = {0.5, 1.0, 2.0};
  const double S[3] = {8.0, 16.0, 32.0};
  double r = R[a / 3], s = S[a - (a / 3) * 3];
  double hd = 16.0 * s * sqrt(r);
  double wd = 16.0 * s * sqrt(1.0 / r);
  float ay1 = (float)(8.0 - hd / 2.0) + (float)(py * 16);
  float ax1 = (float)(8.0 - wd / 2.0) + (float)(px * 16);
  float ay2 = (float)(8.0 + hd / 2.0) + (float)(py * 16);
  float ax2 = (float)(8.0 + wd / 2.0) + (float)(px * 16);
  if (n == 0) {
    float* ao = anchor_out + (size_t)k * 4;
    ao[0] = ay1; ao[1] = ax1; ao[2] = ay2; ao[3] = ax2;
  }
  float ahk = ay2 - ay1, awk = ax2 - ax1;
  float acy = ay1 + 0.5f * ahk, acx = ax1 + 0.5f * awk;
  const float* lp = out0 + ((size_t)(n * NANCH + k) << 2);
  float dy = lp[0], dx = lp[1], dh = lp[2], dw = lp[3];
  float cy = dy * ahk + acy;
  float cx = dx * awk + acx;
  float bh = expf(dh) * ahk;
  float bw = expf(dw) * awk;
  float img_h = (float)imgh_p[0], img_w = (float)imgw_p[0];
  float y1 = fminf(fmaxf(cy - 0.5f * bh, 0.f), img_h);
  float x1 = fminf(fmaxf(cx - 0.5f * bw, 0.f), img_w);
  float y2 = fminf(fmaxf(cy + 0.5f * bh, 0.f), img_h);
  float x2 = fminf(fmaxf(cx + 0.5f * bw, 0.f), img_w);
  bool valid = ((y2 - y1) >= 16.f) && ((x2 - x1) >= 16.f);
  float sc = valid ? fgbuf[n * NANCH + k] : -INFINITY;
  roibuf[n * NANCH + k] = make_float4(y1, x1, y2, x2);
  unsigned int b = __float_as_uint(sc);
  unsigned int m = b ^ ((b & 0x80000000u) ? 0xFFFFFFFFu : 0x80000000u);
  u32 hk = ~m;
  keys[gid] = ((u64)hk << 32) | (unsigned int)k;
  if (hk < 0xFF800000u) atomicAdd(&hist[(n << 16) + (hk >> 16)], 1u);
}

// ---------------------------------------------------------------------------
// 4. R5 fused selection: thresh + compact + sort + gather in ONE kernel.
// 1 block of 1024 per image. Phase 1: scan 65536-bin histogram -> rank-6000
// bin threshold T (4 KB scan scratch aliases the sort array; barrier-
// separated). Phase 2: compact keys with bin <= T into LDS via atomic slot
// counter. Phase 3: 8192-element bitonic sort. Phase 4: sbox/alive gather.
// Replaces 3 kernels + all cnt/cbuf global round-trips.
// ---------------------------------------------------------------------------
__global__ __launch_bounds__(1024) void select_kernel(
    const u32* __restrict__ hist, const u64* __restrict__ keys,
    const float4* __restrict__ roibuf,
    float4* __restrict__ sbox, u64* __restrict__ alive) {
  __shared__ u64 sk[CAP];            // 64 KB
  __shared__ u32 sT, sCnt;
  u32* sc = (u32*)sk;                // phase-1 alias (first 4 KB)
  const int n = blockIdx.x, t = threadIdx.x;

  // ---- phase 1: bin-count scan -> threshold bin T
  const uint4* hp = (const uint4*)(hist + (n << 16));
  u32 s = 0;
#pragma unroll
  for (int q = 0; q < 16; ++q) {
    uint4 v = hp[t * 16 + q];
    s += v.x + v.y + v.z + v.w;
  }
  if (t == 0) { sT = 0u; sCnt = 0u; }
  sc[t] = s;
  __syncthreads();
  for (int off = 1; off < 1024; off <<= 1) {
    u32 v = (t >= off) ? sc[t - off] : 0u;
    __syncthreads();
    sc[t] += v;
    __syncthreads();
  }
  u32 total = sc[1023];
  u32 target = total < (u32)N_PRE ? total : (u32)N_PRE;
  u32 mycum = sc[t];
  u32 prev = t ? sc[t - 1] : 0u;
  __syncthreads();                   // sc reads done before sk re-init
  if (total > 0 && mycum >= target && prev < target) {
    u32 base = prev;
    int b = t << 6;
    while (true) {
      base += hist[(n << 16) + b];
      if (base >= target) break;
      ++b;
    }
    sT = (u32)b;
  }
  __syncthreads();
  const u32 T = sT;
  const bool any = (total > 0);

  // ---- phase 2: init sort array, compact keys with bin <= T
  for (int e = t; e < CAP; e += 1024) sk[e] = ~0ull;
  __syncthreads();
  for (int i = t; i < NANCH; i += 1024) {
    u64 key = keys[(n << 16) + i];
    u32 hk = (u32)(key >> 32);
    if (any && hk < 0xFF800000u && (hk >> 16) <= T) {
      u32 slot = atomicAdd(&sCnt, 1u);
      if (slot < (u32)CAP) sk[slot] = key;
    }
  }
  __syncthreads();

  // ---- phase 3: bitonic sort (ascending)
  for (int k = 2; k <= CAP; k <<= 1) {
    for (int j = k >> 1; j > 0; j >>= 1) {
      for (int q = t; q < (CAP >> 1); q += 1024) {
        int l = ((q & ~(j - 1)) << 1) | (q & (j - 1));
        int rr = l | j;
        bool asc = ((l & k) == 0);
        u64 a = sk[l], b = sk[rr];
        if ((a > b) == asc) { sk[l] = b; sk[rr] = a; }
      }
      __syncthreads();
    }
  }

  // ---- phase 4: gather sbox + alive bitmask
  for (int i = t; i < NPADC; i += 1024) {
    u64 kk = sk[i];
    bool valid = (i < N_PRE) && ((u32)(kk >> 32) < 0xFF800000u);
    float4 b = make_float4(0.f, 0.f, 0.f, 0.f);
    if (valid) b = roibuf[(size_t)n * NANCH + (u32)(kk & 0xFFFFFFFFull)];
    sbox[n * NPADC + i] = b;
    u64 bal = __ballot(valid);
    if ((t & 63) == 0) alive[n * NW + (i >> 6)] = bal;
  }
}

// ---------------------------------------------------------------------------
// 6b. build FULL suppression matrix (both triangles; symmetric).
// ---------------------------------------------------------------------------
__global__ __launch_bounds__(256) void build_mask(
    const float4* __restrict__ sbox, u64* __restrict__ M) {
  __shared__ float4 jb[4][64];
  __shared__ float ja[4][64];
  const int tid = threadIdx.x, lane = tid & 63, wv = tid >> 6;
  const int g = blockIdx.x, q = blockIdx.y, n = blockIdx.z;
  const float4* sb = sbox + n * NPADC;
  float4 bi = sb[(g << 6) + lane];
  float ai = (bi.z - bi.x) * (bi.w - bi.y);
  u64* Mrow = M + ((size_t)(n * NPADC + (g << 6) + lane)) * NW;
#pragma unroll
  for (int it = 0; it < 6; ++it) {
    int w = q * 24 + (it << 2) + wv;
    float4 bjl = sb[(w << 6) + lane];
    jb[wv][lane] = bjl;
    ja[wv][lane] = (bjl.z - bjl.x) * (bjl.w - bjl.y);
    u64 bits = 0;
#pragma unroll 8
    for (int j = 0; j < 64; ++j) {
      float4 bj = jb[wv][j];
      float aj = ja[wv][j];
      float ih = fmaxf(fminf(bi.z, bj.z) - fmaxf(bi.x, bj.x), 0.f);
      float iw = fmaxf(fminf(bi.w, bj.w) - fmaxf(bi.y, bj.y), 0.f);
      float inter = ih * iw;
      bool bit = inter / (ai + aj - inter + 1e-9f) > 0.7f;
      bits |= ((u64)bit) << j;
    }
    Mrow[w] = bits;
  }
}

// ---------------------------------------------------------------------------
// 6c. serial greedy reduce, one wave per image.
// ---------------------------------------------------------------------------
__global__ __launch_bounds__(64) void nms_reduce(
    const u64* __restrict__ M, const u64* __restrict__ alive,
    const float4* __restrict__ sbox, float* __restrict__ out) {
  const int n = blockIdx.x, lane = threadIdx.x;
  float* rois = out + O2 + n * (N_POST * 4);
  float* vmask = out + O5 + n * N_POST;
  const u64* A = alive + n * NW;
  const u64* Mb = M + (size_t)n * NPADC * NW;
  const float4* sb = sbox + n * NPADC;
  u64 aw0 = A[lane];
  u64 aw1 = (lane < 32) ? A[64 + lane] : 0ull;
  u64 accA = 0, accB = 0;
  int nk = 0;
  u64 dnext = Mb[(size_t)lane * NW + 0];
  float4 bnext = sb[lane];
  const u64 below = lane ? (~0ull >> (64 - lane)) : 0ull;

  for (int c = 0; c < 94; ++c) {
    u64 dcur = dnext;
    float4 bcur = bnext;
    if (c + 1 < 94) {
      dnext = Mb[(size_t)(((c + 1) << 6) + lane) * NW + (c + 1)];
      bnext = sb[((c + 1) << 6) + lane];
    }
    u64 wacc = (c < 64) ? bcast64(accA, c) : bcast64(accB, c - 64);
    u64 aw = (c < 64) ? bcast64(aw0, c) : bcast64(aw1, c - 64);
    u64 alive_u = aw & ~wacc;
    if (alive_u == 0ull) continue;

    u64 dmask = dcur & below;
    u64 rem = alive_u, kept = 0;
    while (rem) {
      int j = __builtin_ctzll(rem);
      kept |= 1ull << j;
      u64 col = __ballot((dmask >> j) & 1);
      rem &= ~(col | (1ull << j));
    }

    int npop = __popcll(kept);
    if ((kept >> lane) & 1ull) {
      int slot = nk + __popcll(kept & below);
      if (slot < N_POST) {
        rois[slot * 4 + 0] = bcur.x; rois[slot * 4 + 1] = bcur.y;
        rois[slot * 4 + 2] = bcur.z; rois[slot * 4 + 3] = bcur.w;
        vmask[slot] = 1.0f;
      }
    }
    if (nk + npop >= N_POST) break;
    nk += npop;

    u64 kk = kept;
    while (kk) {
      int j0 = __builtin_ctzll(kk); kk &= kk - 1;
      int j1 = kk ? __builtin_ctzll(kk) : j0; kk &= kk - 1;
      int j2 = kk ? __builtin_ctzll(kk) : j0; kk &= kk - 1;
      int j3 = kk ? __builtin_ctzll(kk) : j0; kk &= kk - 1;
      int j4 = kk ? __builtin_ctzll(kk) : j0; kk &= kk - 1;
      int j5 = kk ? __builtin_ctzll(kk) : j0; kk &= kk - 1;
      int j6 = kk ? __builtin_ctzll(kk) : j0; kk &= kk - 1;
      int j7 = kk ? __builtin_ctzll(kk) : j0; kk &= kk - 1;
      const u64* r0 = Mb + (size_t)((c << 6) + j0) * NW;
      const u64* r1 = Mb + (size_t)((c << 6) + j1) * NW;
      const u64* r2 = Mb + (size_t)((c << 6) + j2) * NW;
      const u64* r3 = Mb + (size_t)((c << 6) + j3) * NW;
      const u64* r4 = Mb + (size_t)((c << 6) + j4) * NW;
      const u64* r5 = Mb + (size_t)((c << 6) + j5) * NW;
      const u64* r6 = Mb + (size_t)((c << 6) + j6) * NW;
      const u64* r7 = Mb + (size_t)((c << 6) + j7) * NW;
      u64 oA = r0[lane] | r1[lane] | r2[lane] | r3[lane]
             | r4[lane] | r5[lane] | r6[lane] | r7[lane];
      u64 oB = 0;
      if (lane < 32)
        oB = r0[64 + lane] | r1[64 + lane] | r2[64 + lane] | r3[64 + lane]
           | r4[64 + lane] | r5[64 + lane] | r6[64 + lane] | r7[64 + lane];
      accA |= oA;
      accB |= oB;
    }
  }
}

// ---------------------------------------------------------------------------
extern "C" void kernel_launch(void* const* d_in, const int* in_sizes, int n_in,
                              void* d_out, int out_size, void* d_ws, size_t ws_size,
                              hipStream_t stream) {
  const float* x        = (const float*)d_in[0];
  const float* conv1_w  = (const float*)d_in[1];
  const float* conv1_b  = (const float*)d_in[2];
  const float* score_w  = (const float*)d_in[3];
  const float* score_b  = (const float*)d_in[4];
  const float* loc_w    = (const float*)d_in[5];
  const float* loc_b    = (const float*)d_in[6];
  const int*   imgh_p   = (const int*)d_in[7];
  const int*   imgw_p   = (const int*)d_in[8];

  float* out = (float*)d_out;
  float* ws  = (float*)d_ws;

  _Float16* xhi = (_Float16*)(ws + WS_XHI);
  _Float16* xlo = (_Float16*)(ws + WS_XLO);
  _Float16* whi = (_Float16*)(ws + WS_WHI);
  _Float16* wlo = (_Float16*)(ws + WS_WLO);
  float* wslt   = ws + WS_WSLT;
  float* wslb   = ws + WS_WSLB;
  float* hbuf   = ws + WS_H;
  float* guard  = ws + WS_GUARD;
  // overlays (xhi region is dead after conv)
  float* fgbuf   = ws + WS_FG;
  float4* roibuf = (float4*)(ws + WS_ROI);
  u64* keys      = (u64*)(ws + WS_KEYS);
  float4* sbox   = (float4*)(ws + WS_SBOX);
  u64* alive     = (u64*)(ws + WS_ALIVE);
  u32* hist      = (u32*)(ws + WS_HIST);
  u64* maskbuf   = (u64*)(ws + WS_MASK);   // overlays whi/wlo (dead after conv)

  prep_all<<<5826, 256, 0, stream>>>(x, conv1_w, loc_w, score_w, loc_b, score_b,
                                     (float4*)hbuf, (float4*)guard,
                                     xhi, xlo, whi, wlo, wslt, wslb);

  conv_mfma<<<dim3(64, 4, 2), 256, 0, stream>>>(xhi, xlo, whi, wlo, guard, hbuf);

  head_kernel<<<dim3(64, 2), 256, 0, stream>>>(hbuf, conv1_b, wslt, wslb, out,
                                               fgbuf, (uint4*)hist);
  decode_kernel<<<512, 256, 0, stream>>>(out, fgbuf, roibuf, keys,
                                         out + O4, out, hist, imgh_p, imgw_p);

  select_kernel<<<2, 1024, 0, stream>>>(hist, keys, roibuf, sbox, alive);

  build_mask<<<dim3(96, 4, 2), 256, 0, stream>>>(sbox, maskbuf);
  nms_reduce<<<2, 64, 0, stream>>>(maskbuf, alive, sbox, out);
}

// Round 6
// 490.803 us; speedup vs baseline: 1.2026x; 1.0092x over previous
//
#include <hip/hip_runtime.h>
#include <hip/hip_bf16.h>
#include <math.h>
#include <cstdint>

typedef unsigned long long u64;
typedef unsigned int u32;
typedef _Float16 half8 __attribute__((ext_vector_type(8)));
typedef float floatx4 __attribute__((ext_vector_type(4)));

// ---------------------------------------------------------------------------
// Sizes
// ---------------------------------------------------------------------------
#define NANCH 36864        // 4096*9
#define SEG 65536          // per-image key segment stride (layout only)
#define N_PRE 6000
#define N_POST 300
#define NW 96              // mask words per row (6144 bits)
#define NPADC 6144         // padded candidate count
#define CAP 8192           // compaction buffer capacity per image

// output float offsets
#define O0 0               // rpn_locs  2*36864*4 = 294912
#define O1 294912          // rpn_scores 2*36864*2 = 147456
#define O2 442368          // rois 2*300*4 = 2400
#define O3 444768          // roi_indices 600
#define O4 445368          // anchor 147456
#define O5 592824          // vmask 600

// workspace float offsets
#define WS_XHI   0                        // xhi f16 [2][4096][512] (2,097,152 f)
#define WS_XLO   2097152
#define WS_WHI   4194304                  // whi f16 [9][512][512] (1,179,648 f)
#define WS_WLO   5373952
#define WS_WSLT  6553600                  // 32768
#define WS_WSLB  6586368                  // 64
#define WS_H     6586432                  // hbuf f32 [2][4096][512] = 4,194,304 f
#define WS_GUARD 10780736                 // 64 floats of zeros (OOB target)
// overlays into dead XHI region (used only after conv completes):
#define WS_FG    0                        // 73728
#define WS_ROI   73728                    // 294912 (16B aligned)
#define WS_KEYS  368640                   // 131072 u64 = 262144 f
#define WS_SBOX  630784                   // 2*6144 float4 = 49152 f
#define WS_ALIVE 679936                   // 2*96 u64 = 384 f
#define WS_HIST  713088                   // 2*65536 u32 = 131072 f
// overlay into dead WHI+WLO region (after conv): FULL suppression matrix
#define WS_MASK  4194304                  // 2*6144*96 u64 = 9,437,184 B (exact fit)

#define HSCALE 9.5367431640625e-07f       // 2^-20

// ---------------------------------------------------------------------------
__device__ __forceinline__ void gl_lds16(const void* g, void* l) {
  __builtin_amdgcn_global_load_lds(
      (const __attribute__((address_space(1))) u32*)g,
      (__attribute__((address_space(3))) u32*)l, 16, 0, 0);
}

__device__ __forceinline__ u64 bcast64(u64 v, int src) {
  u32 lo = (u32)__shfl((int)(v & 0xFFFFFFFFull), src);
  u32 hi = (u32)__shfl((int)(v >> 32), src);
  return ((u64)hi << 32) | lo;
}

// ---------------------------------------------------------------------------
// 0. fused prep: zero hbuf+guard | xcvt | wcvt | head-weight pack.
// ---------------------------------------------------------------------------
__global__ __launch_bounds__(256) void prep_all(
    const float* __restrict__ x, const float* __restrict__ w,
    const float* __restrict__ lw, const float* __restrict__ sw,
    const float* __restrict__ lb, const float* __restrict__ sb,
    float4* __restrict__ h, float4* __restrict__ guard,
    _Float16* __restrict__ xhi, _Float16* __restrict__ xlo,
    _Float16* __restrict__ whi, _Float16* __restrict__ wlo,
    float* __restrict__ wslt, float* __restrict__ wslb) {
  __shared__ float s[64 * 65];
  const int b = blockIdx.x, tid = threadIdx.x;
  if (b < 4097) {
    int idx = b * 256 + tid;
    if (idx < 1048576) h[idx] = make_float4(0.f, 0.f, 0.f, 0.f);
    else if (idx < 1048576 + 16) guard[idx - 1048576] = make_float4(0.f, 0.f, 0.f, 0.f);
    return;
  }
  if (b < 5121) {  // xcvt: [n][c][pix] f32 -> [n][pix][c] f16 hi/lo x1024
    int l = b - 4097;
    int pt = l & 63, cg = (l >> 6) & 7, n = l >> 9;
    const int c0 = cg << 6, p0 = pt << 6;
#pragma unroll
    for (int kk = 0; kk < 16; ++kk) {
      int e = tid + (kk << 8);
      int ci = e >> 6, pi = e & 63;
      s[ci * 65 + pi] = x[(((size_t)(n * 512 + c0 + ci)) << 12) + p0 + pi];
    }
    __syncthreads();
#pragma unroll
    for (int kk = 0; kk < 16; ++kk) {
      int e = tid + (kk << 8);
      int ci = e & 63, pi = e >> 6;
      float sv = s[ci * 65 + pi] * 1024.f;
      _Float16 hi = (_Float16)sv;
      _Float16 lo = (_Float16)(sv - (float)hi);
      size_t off = (((size_t)(n << 12) + p0 + pi) << 9) + c0 + ci;
      xhi[off] = hi;
      xlo[off] = lo;
    }
    return;
  }
  if (b < 5697) {  // wcvt: [o][c][3][3] -> [t][o][c] f16 hi/lo x1024
    int l = b - 5121;
    int ct = l & 7, ot = (l >> 3) & 7, t = l >> 6;
    const int c0 = ct << 6, o0 = ot << 6;
#pragma unroll
    for (int kk = 0; kk < 16; ++kk) {
      int e = tid + (kk << 8);
      int ci = e & 63, oi = e >> 6;
      float sv = w[(size_t)(o0 + oi) * 4608 + (c0 + ci) * 9 + t] * 1024.f;
      _Float16 hi = (_Float16)sv;
      _Float16 lo = (_Float16)(sv - (float)hi);
      size_t off = ((size_t)((t << 9) + o0 + oi) << 9) + c0 + ci;
      whi[off] = hi;
      wlo[off] = lo;
    }
    return;
  }
  {  // prep_small
    int e = (b - 5697) * 256 + tid;
    if (e < 32768) {
      int c = e >> 6, o = e & 63;
      float v = 0.f;
      if (o < 36) v = lw[o * 512 + c];
      else if (o < 54) v = sw[(o - 36) * 512 + c];
      wslt[e] = v;
    } else if (e < 32832) {
      int o = e - 32768;
      float v = 0.f;
      if (o < 36) v = lb[o];
      else if (o < 54) v = sb[o - 36];
      wslb[o] = v;
    }
  }
}

// ---------------------------------------------------------------------------
// 1. MFMA implicit-GEMM 3x3 conv (fp16x2 split: hh + hl + lh, fp32 acc).
// R0 structure, parked: 121us = ~960 TF effective on the 3-pass GEMM —
// at the plain-HIP 2-barrier-structure ceiling (m97/m103). Perturbations
// all regressed: R1 pipelined dbuf 129 | R2 pass-split 217 | R3 B-in-regs
// 169. Do not touch.
// ---------------------------------------------------------------------------
__global__ __launch_bounds__(256) void conv_mfma(
    const _Float16* __restrict__ xhi, const _Float16* __restrict__ xlo,
    const _Float16* __restrict__ whi, const _Float16* __restrict__ wlo,
    const float* __restrict__ guard, float* __restrict__ hout) {
  __shared__ _Float16 aHi[4 * 68 * 32];
  __shared__ _Float16 aLo[4 * 68 * 32];
  __shared__ _Float16 bHi[128 * 32];
  __shared__ _Float16 bLo[128 * 32];
  const int tid = threadIdx.x;
  const int lane = tid & 63, w = tid >> 6;
  const int ptile = blockIdx.x;
  const int og = blockIdx.y;
  const int kq = blockIdx.z;
  const int n = ptile >> 5;
  const int y0 = (ptile & 31) << 1;
  const int o0 = og << 7;
  const int l15 = lane & 15, l16 = lane >> 4;
  const int ry = w >> 1;
  const int wo = (w & 1) << 6;

  floatx4 acc[4][4];
#pragma unroll
  for (int a = 0; a < 4; ++a)
#pragma unroll
    for (int b = 0; b < 4; ++b) acc[a][b] = (floatx4)0.f;

  for (int s = 0; s < 8; ++s) {
    const int c0 = (kq << 8) + (s << 5);
    __syncthreads();
    for (int i = w; i < 17; i += 4) {
      int chunk = (i << 6) + lane;
      int p = chunk >> 2, q = chunk & 3;
      int r = p / 68, xs = p - r * 68;
      int y = y0 - 1 + r, xg = xs - 1;
      bool ok = ((unsigned)y < 64u) && ((unsigned)xg < 64u);
      size_t off = (((size_t)(n << 12) + (y << 6) + xg) << 9) + c0 + (q << 3);
      const void* gh = ok ? (const void*)(xhi + off) : (const void*)guard;
      const void* gl = ok ? (const void*)(xlo + off) : (const void*)guard;
      gl_lds16(gh, (char*)aHi + (i << 10));
      gl_lds16(gl, (char*)aLo + (i << 10));
    }
    for (int tt = 0; tt < 9; ++tt) {
      if (tt > 0) __syncthreads();
      for (int i = w; i < 8; i += 4) {
        int chunk = (i << 6) + lane;
        int row = chunk >> 2, q = chunk & 3;
        size_t off = ((size_t)((tt << 9) + o0 + row) << 9) + c0 + (q << 3);
        gl_lds16((const void*)(whi + off), (char*)bHi + (i << 10));
        gl_lds16((const void*)(wlo + off), (char*)bLo + (i << 10));
      }
      __syncthreads();

      const int dy = tt / 3, dx = tt - 3 * dy;
      half8 ah[4], al[4], bh[4], bl[4];
#pragma unroll
      for (int im = 0; im < 4; ++im) {
        int xp = (im << 4) + l15;
        int p = (ry + dy) * 68 + xp + dx;
        ah[im] = *(const half8*)&aHi[(p << 5) + (l16 << 3)];
        al[im] = *(const half8*)&aLo[(p << 5) + (l16 << 3)];
      }
#pragma unroll
      for (int in = 0; in < 4; ++in) {
        int orow = wo + (in << 4) + l15;
        bh[in] = *(const half8*)&bHi[(orow << 5) + (l16 << 3)];
        bl[in] = *(const half8*)&bLo[(orow << 5) + (l16 << 3)];
      }
#pragma unroll
      for (int im = 0; im < 4; ++im)
#pragma unroll
        for (int in = 0; in < 4; ++in) {
          acc[im][in] = __builtin_amdgcn_mfma_f32_16x16x32_f16(
              ah[im], bh[in], acc[im][in], 0, 0, 0);
          acc[im][in] = __builtin_amdgcn_mfma_f32_16x16x32_f16(
              ah[im], bl[in], acc[im][in], 0, 0, 0);
          acc[im][in] = __builtin_amdgcn_mfma_f32_16x16x32_f16(
              al[im], bh[in], acc[im][in], 0, 0, 0);
        }
    }
  }

#pragma unroll
  for (int im = 0; im < 4; ++im)
#pragma unroll
    for (int in = 0; in < 4; ++in) {
      int o = o0 + wo + (in << 4) + l15;
#pragma unroll
      for (int reg = 0; reg < 4; ++reg) {
        int m_local = (ry << 6) + (im << 4) + (l16 << 2) + reg;
        size_t off = (((size_t)(n << 12) + (y0 << 6) + m_local) << 9) + o;
        atomicAdd(&hout[off], acc[im][in][reg]);
      }
    }
}

// ---------------------------------------------------------------------------
// 2. 1x1 heads + softmax. R6: grid (64 y, 2 n, 4 xq), block 256.
// Was 128 blocks (half the CUs idle, 1 wave/SIMD, exposed LDS latency,
// est 30-40us). Now 512 blocks = 2 blocks/CU; each handles a 16-pixel
// x-quarter with 16 og-groups x 4 outputs (acc[4], 2048 FMA/thread).
// Accumulation order per output unchanged -> bit-identical results.
// ---------------------------------------------------------------------------
__global__ __launch_bounds__(256) void head_kernel(
    const float* __restrict__ hbuf, const float* __restrict__ cb,
    const float* __restrict__ wslt, const float* __restrict__ wslb,
    float* __restrict__ out, float* __restrict__ fgbuf,
    uint4* __restrict__ hist4) {
  const int y = blockIdx.x, n = blockIdx.y, xq = blockIdx.z;
  __shared__ float sH[16 * 17];
  __shared__ float sWt[1024];
  __shared__ float sOut[64 * 17];
  const int tid = threadIdx.x;
  const int x4 = tid & 15, og = tid >> 4;   // 16 x-positions, 16 out-groups
  const int x0 = xq << 4;                    // x-quarter base

  // init for the selection path (xq==0 blocks: 128 x 256 = 32768 lanes)
  if (xq == 0) {
    int gid = ((n << 6) + y) * 256 + tid;          // 0..32767
    hist4[gid] = make_uint4(0u, 0u, 0u, 0u);       // 32768*16B = 512 KB = hist
  }

  float acc[4];
#pragma unroll
  for (int j = 0; j < 4; ++j) acc[j] = 0.f;

  const float* hb = hbuf + (((size_t)(n << 12) + (y << 6) + x0) << 9);

  for (int c0 = 0; c0 < 512; c0 += 16) {
    __syncthreads();
    {  // stage sH: 16 ch x 16 x = 256 elems (1/thread)
      int cc = tid & 15, xx = tid >> 4;
      float raw = hb[((size_t)xx << 9) + c0 + cc];
      sH[cc * 17 + xx] = fmaxf(raw * HSCALE + cb[c0 + cc], 0.f);
    }
#pragma unroll
    for (int p = 0; p < 4; ++p) {  // stage sWt: 16 ch x 64 out = 1024
      int e = tid + (p << 8);
      int cc = e >> 6, xx = e & 63;
      sWt[e] = wslt[((c0 + cc) << 6) + xx];
    }
    __syncthreads();
#pragma unroll
    for (int cc = 0; cc < 16; ++cc) {
      float hv = sH[cc * 17 + x4];
      float4 w0 = *(const float4*)&sWt[(cc << 6) + (og << 2)];
      acc[0] = fmaf(hv, w0.x, acc[0]);
      acc[1] = fmaf(hv, w0.y, acc[1]);
      acc[2] = fmaf(hv, w0.z, acc[2]);
      acc[3] = fmaf(hv, w0.w, acc[3]);
    }
  }
  __syncthreads();
#pragma unroll
  for (int j = 0; j < 4; ++j) {
    int o = (og << 2) + j;
    sOut[o * 17 + x4] = acc[j] + wslb[o];
  }
  __syncthreads();

  const int p0 = (n << 12) + (y << 6);
  float* locs = out + O0 + (size_t)p0 * 36 + (size_t)x0 * 36;
  for (int e = tid; e < 576; e += 256) {
    int xx = e / 36, o = e - xx * 36;
    locs[e] = sOut[o * 17 + xx];
  }
  float* scrs = out + O1 + (size_t)p0 * 18 + (size_t)x0 * 18;
  for (int e = tid; e < 288; e += 256) {
    int xx = e / 18, ss = e - xx * 18;
    scrs[e] = sOut[(36 + ss) * 17 + xx];
  }
  float* fg = fgbuf + n * NANCH + ((y << 6) + x0) * 9;
  for (int e = tid; e < 144; e += 256) {
    int xx = e / 9, a = e - xx * 9;
    float s0 = sOut[(36 + 2 * a) * 17 + xx];
    float s1 = sOut[(36 + 2 * a + 1) * 17 + xx];
    fg[e] = 1.0f / (1.0f + expf(s0 - s1));
  }
}

// ---------------------------------------------------------------------------
// 3. anchors + decode + clip + min-size + sort keys + FUSED histogram.
// ---------------------------------------------------------------------------
__global__ __launch_bounds__(256) void decode_kernel(
    const float* __restrict__ out0, const float* __restrict__ fgbuf,
    float4* __restrict__ roibuf, u64* __restrict__ keys,
    float* __restrict__ anchor_out, float* __restrict__ out,
    u32* __restrict__ hist,
    const int* __restrict__ imgh_p, const int* __restrict__ imgw_p) {
  int gid = blockIdx.x * 256 + threadIdx.x;   // < 131072
  if (gid < 3600) {
    if (gid < 2400) out[O2 + gid] = 0.f;
    else if (gid < 3000) out[O3 + (gid - 2400)] = (float)((gid - 2400) / 300);
    else out[O5 + (gid - 3000)] = 0.f;
  }
  int n = gid >> 16, k = gid & (SEG - 1);
  if (k >= NANCH) return;
  int a = k % 9;
  int p = k / 9;
  int py = p >> 6, px = p & 63;

  const double R[3] = {0.5, 1.0, 2.0};
  const double S[3] = {8.0, 16.0, 32.0};
  double r = R[a / 3], s = S[a - (a / 3) * 3];
  double hd = 16.0 * s * sqrt(r);
  double wd = 16.0 * s * sqrt(1.0 / r);
  float ay1 = (float)(8.0 - hd / 2.0) + (float)(py * 16);
  float ax1 = (float)(8.0 - wd / 2.0) + (float)(px * 16);
  float ay2 = (float)(8.0 + hd / 2.0) + (float)(py * 16);
  float ax2 = (float)(8.0 + wd / 2.0) + (float)(px * 16);
  if (n == 0) {
    float* ao = anchor_out + (size_t)k * 4;
    ao[0] = ay1; ao[1] = ax1; ao[2] = ay2; ao[3] = ax2;
  }
  float ahk = ay2 - ay1, awk = ax2 - ax1;
  float acy = ay1 + 0.5f * ahk, acx = ax1 + 0.5f * awk;
  const float* lp = out0 + ((size_t)(n * NANCH + k) << 2);
  float dy = lp[0], dx = lp[1], dh = lp[2], dw = lp[3];
  float cy = dy * ahk + acy;
  float cx = dx * awk + acx;
  float bh = expf(dh) * ahk;
  float bw = expf(dw) * awk;
  float img_h = (float)imgh_p[0], img_w = (float)imgw_p[0];
  float y1 = fminf(fmaxf(cy - 0.5f * bh, 0.f), img_h);
  float x1 = fminf(fmaxf(cx - 0.5f * bw, 0.f), img_w);
  float y2 = fminf(fmaxf(cy + 0.5f * bh, 0.f), img_h);
  float x2 = fminf(fmaxf(cx + 0.5f * bw, 0.f), img_w);
  bool valid = ((y2 - y1) >= 16.f) && ((x2 - x1) >= 16.f);
  float sc = valid ? fgbuf[n * NANCH + k] : -INFINITY;
  roibuf[n * NANCH + k] = make_float4(y1, x1, y2, x2);
  unsigned int b = __float_as_uint(sc);
  unsigned int m = b ^ ((b & 0x80000000u) ? 0xFFFFFFFFu : 0x80000000u);
  u32 hk = ~m;
  keys[gid] = ((u64)hk << 32) | (unsigned int)k;
  if (hk < 0xFF800000u) atomicAdd(&hist[(n << 16) + (hk >> 16)], 1u);
}

// ---------------------------------------------------------------------------
// 4. fused selection: thresh + compact + sort + gather in ONE kernel.
// ---------------------------------------------------------------------------
__global__ __launch_bounds__(1024) void select_kernel(
    const u32* __restrict__ hist, const u64* __restrict__ keys,
    const float4* __restrict__ roibuf,
    float4* __restrict__ sbox, u64* __restrict__ alive) {
  __shared__ u64 sk[CAP];            // 64 KB
  __shared__ u32 sT, sCnt;
  u32* sc = (u32*)sk;                // phase-1 alias (first 4 KB)
  const int n = blockIdx.x, t = threadIdx.x;

  // ---- phase 1: bin-count scan -> threshold bin T
  const uint4* hp = (const uint4*)(hist + (n << 16));
  u32 s = 0;
#pragma unroll
  for (int q = 0; q < 16; ++q) {
    uint4 v = hp[t * 16 + q];
    s += v.x + v.y + v.z + v.w;
  }
  if (t == 0) { sT = 0u; sCnt = 0u; }
  sc[t] = s;
  __syncthreads();
  for (int off = 1; off < 1024; off <<= 1) {
    u32 v = (t >= off) ? sc[t - off] : 0u;
    __syncthreads();
    sc[t] += v;
    __syncthreads();
  }
  u32 total = sc[1023];
  u32 target = total < (u32)N_PRE ? total : (u32)N_PRE;
  u32 mycum = sc[t];
  u32 prev = t ? sc[t - 1] : 0u;
  __syncthreads();                   // sc reads done before sk re-init
  if (total > 0 && mycum >= target && prev < target) {
    u32 base = prev;
    int b = t << 6;
    while (true) {
      base += hist[(n << 16) + b];
      if (base >= target) break;
      ++b;
    }
    sT = (u32)b;
  }
  __syncthreads();
  const u32 T = sT;
  const bool any = (total > 0);

  // ---- phase 2: init sort array, compact keys with bin <= T
  for (int e = t; e < CAP; e += 1024) sk[e] = ~0ull;
  __syncthreads();
  for (int i = t; i < NANCH; i += 1024) {
    u64 key = keys[(n << 16) + i];
    u32 hk = (u32)(key >> 32);
    if (any && hk < 0xFF800000u && (hk >> 16) <= T) {
      u32 slot = atomicAdd(&sCnt, 1u);
      if (slot < (u32)CAP) sk[slot] = key;
    }
  }
  __syncthreads();

  // ---- phase 3: bitonic sort (ascending)
  for (int k = 2; k <= CAP; k <<= 1) {
    for (int j = k >> 1; j > 0; j >>= 1) {
      for (int q = t; q < (CAP >> 1); q += 1024) {
        int l = ((q & ~(j - 1)) << 1) | (q & (j - 1));
        int rr = l | j;
        bool asc = ((l & k) == 0);
        u64 a = sk[l], b = sk[rr];
        if ((a > b) == asc) { sk[l] = b; sk[rr] = a; }
      }
      __syncthreads();
    }
  }

  // ---- phase 4: gather sbox + alive bitmask
  for (int i = t; i < NPADC; i += 1024) {
    u64 kk = sk[i];
    bool valid = (i < N_PRE) && ((u32)(kk >> 32) < 0xFF800000u);
    float4 b = make_float4(0.f, 0.f, 0.f, 0.f);
    if (valid) b = roibuf[(size_t)n * NANCH + (u32)(kk & 0xFFFFFFFFull)];
    sbox[n * NPADC + i] = b;
    u64 bal = __ballot(valid);
    if ((t & 63) == 0) alive[n * NW + (i >> 6)] = bal;
  }
}

// ---------------------------------------------------------------------------
// 6b. build suppression matrix — R6: UPPER-TRIANGLE only (w >= g).
// nms_reduce provably never consumes word w of a row in chunk g when
// w < g: row j (chunk c_j) only feeds acc words consumed at chunks
// c' > c_j (its OR happens after chunk c_j's consumption point), and
// its valid words are w >= c_j. Halves IoU work and mask writes.
// ---------------------------------------------------------------------------
__global__ __launch_bounds__(256) void build_mask(
    const float4* __restrict__ sbox, u64* __restrict__ M) {
  __shared__ float4 jb[4][64];
  __shared__ float ja[4][64];
  const int tid = threadIdx.x, lane = tid & 63, wv = tid >> 6;
  const int g = blockIdx.x, q = blockIdx.y, n = blockIdx.z;
  const float4* sb = sbox + n * NPADC;
  float4 bi = sb[(g << 6) + lane];
  float ai = (bi.z - bi.x) * (bi.w - bi.y);
  u64* Mrow = M + ((size_t)(n * NPADC + (g << 6) + lane)) * NW;
#pragma unroll
  for (int it = 0; it < 6; ++it) {
    int w = q * 24 + (it << 2) + wv;
    if (w < g) continue;                 // dead lower-triangle word
    float4 bjl = sb[(w << 6) + lane];
    jb[wv][lane] = bjl;
    ja[wv][lane] = (bjl.z - bjl.x) * (bjl.w - bjl.y);
    u64 bits = 0;
#pragma unroll 8
    for (int j = 0; j < 64; ++j) {
      float4 bj = jb[wv][j];
      float aj = ja[wv][j];
      float ih = fmaxf(fminf(bi.z, bj.z) - fmaxf(bi.x, bj.x), 0.f);
      float iw = fmaxf(fminf(bi.w, bj.w) - fmaxf(bi.y, bj.y), 0.f);
      float inter = ih * iw;
      bool bit = inter / (ai + aj - inter + 1e-9f) > 0.7f;
      bits |= ((u64)bit) << j;
    }
    Mrow[w] = bits;
  }
}

// ---------------------------------------------------------------------------
// 6c. serial greedy reduce, one wave per image.
// ---------------------------------------------------------------------------
__global__ __launch_bounds__(64) void nms_reduce(
    const u64* __restrict__ M, const u64* __restrict__ alive,
    const float4* __restrict__ sbox, float* __restrict__ out) {
  const int n = blockIdx.x, lane = threadIdx.x;
  float* rois = out + O2 + n * (N_POST * 4);
  float* vmask = out + O5 + n * N_POST;
  const u64* A = alive + n * NW;
  const u64* Mb = M + (size_t)n * NPADC * NW;
  const float4* sb = sbox + n * NPADC;
  u64 aw0 = A[lane];
  u64 aw1 = (lane < 32) ? A[64 + lane] : 0ull;
  u64 accA = 0, accB = 0;
  int nk = 0;
  u64 dnext = Mb[(size_t)lane * NW + 0];
  float4 bnext = sb[lane];
  const u64 below = lane ? (~0ull >> (64 - lane)) : 0ull;

  for (int c = 0; c < 94; ++c) {
    u64 dcur = dnext;
    float4 bcur = bnext;
    if (c + 1 < 94) {
      dnext = Mb[(size_t)(((c + 1) << 6) + lane) * NW + (c + 1)];
      bnext = sb[((c + 1) << 6) + lane];
    }
    u64 wacc = (c < 64) ? bcast64(accA, c) : bcast64(accB, c - 64);
    u64 aw = (c < 64) ? bcast64(aw0, c) : bcast64(aw1, c - 64);
    u64 alive_u = aw & ~wacc;
    if (alive_u == 0ull) continue;

    u64 dmask = dcur & below;
    u64 rem = alive_u, kept = 0;
    while (rem) {
      int j = __builtin_ctzll(rem);
      kept |= 1ull << j;
      u64 col = __ballot((dmask >> j) & 1);
      rem &= ~(col | (1ull << j));
    }

    int npop = __popcll(kept);
    if ((kept >> lane) & 1ull) {
      int slot = nk + __popcll(kept & below);
      if (slot < N_POST) {
        rois[slot * 4 + 0] = bcur.x; rois[slot * 4 + 1] = bcur.y;
        rois[slot * 4 + 2] = bcur.z; rois[slot * 4 + 3] = bcur.w;
        vmask[slot] = 1.0f;
      }
    }
    if (nk + npop >= N_POST) break;
    nk += npop;

    u64 kk = kept;
    while (kk) {
      int j0 = __builtin_ctzll(kk); kk &= kk - 1;
      int j1 = kk ? __builtin_ctzll(kk) : j0; kk &= kk - 1;
      int j2 = kk ? __builtin_ctzll(kk) : j0; kk &= kk - 1;
      int j3 = kk ? __builtin_ctzll(kk) : j0; kk &= kk - 1;
      int j4 = kk ? __builtin_ctzll(kk) : j0; kk &= kk - 1;
      int j5 = kk ? __builtin_ctzll(kk) : j0; kk &= kk - 1;
      int j6 = kk ? __builtin_ctzll(kk) : j0; kk &= kk - 1;
      int j7 = kk ? __builtin_ctzll(kk) : j0; kk &= kk - 1;
      const u64* r0 = Mb + (size_t)((c << 6) + j0) * NW;
      const u64* r1 = Mb + (size_t)((c << 6) + j1) * NW;
      const u64* r2 = Mb + (size_t)((c << 6) + j2) * NW;
      const u64* r3 = Mb + (size_t)((c << 6) + j3) * NW;
      const u64* r4 = Mb + (size_t)((c << 6) + j4) * NW;
      const u64* r5 = Mb + (size_t)((c << 6) + j5) * NW;
      const u64* r6 = Mb + (size_t)((c << 6) + j6) * NW;
      const u64* r7 = Mb + (size_t)((c << 6) + j7) * NW;
      u64 oA = r0[lane] | r1[lane] | r2[lane] | r3[lane]
             | r4[lane] | r5[lane] | r6[lane] | r7[lane];
      u64 oB = 0;
      if (lane < 32)
        oB = r0[64 + lane] | r1[64 + lane] | r2[64 + lane] | r3[64 + lane]
           | r4[64 + lane] | r5[64 + lane] | r6[64 + lane] | r7[64 + lane];
      accA |= oA;
      accB |= oB;
    }
  }
}

// ---------------------------------------------------------------------------
extern "C" void kernel_launch(void* const* d_in, const int* in_sizes, int n_in,
                              void* d_out, int out_size, void* d_ws, size_t ws_size,
                              hipStream_t stream) {
  const float* x        = (const float*)d_in[0];
  const float* conv1_w  = (const float*)d_in[1];
  const float* conv1_b  = (const float*)d_in[2];
  const float* score_w  = (const float*)d_in[3];
  const float* score_b  = (const float*)d_in[4];
  const float* loc_w    = (const float*)d_in[5];
  const float* loc_b    = (const float*)d_in[6];
  const int*   imgh_p   = (const int*)d_in[7];
  const int*   imgw_p   = (const int*)d_in[8];

  float* out = (float*)d_out;
  float* ws  = (float*)d_ws;

  _Float16* xhi = (_Float16*)(ws + WS_XHI);
  _Float16* xlo = (_Float16*)(ws + WS_XLO);
  _Float16* whi = (_Float16*)(ws + WS_WHI);
  _Float16* wlo = (_Float16*)(ws + WS_WLO);
  float* wslt   = ws + WS_WSLT;
  float* wslb   = ws + WS_WSLB;
  float* hbuf   = ws + WS_H;
  float* guard  = ws + WS_GUARD;
  // overlays (xhi region is dead after conv)
  float* fgbuf   = ws + WS_FG;
  float4* roibuf = (float4*)(ws + WS_ROI);
  u64* keys      = (u64*)(ws + WS_KEYS);
  float4* sbox   = (float4*)(ws + WS_SBOX);
  u64* alive     = (u64*)(ws + WS_ALIVE);
  u32* hist      = (u32*)(ws + WS_HIST);
  u64* maskbuf   = (u64*)(ws + WS_MASK);   // overlays whi/wlo (dead after conv)

  prep_all<<<5826, 256, 0, stream>>>(x, conv1_w, loc_w, score_w, loc_b, score_b,
                                     (float4*)hbuf, (float4*)guard,
                                     xhi, xlo, whi, wlo, wslt, wslb);

  conv_mfma<<<dim3(64, 4, 2), 256, 0, stream>>>(xhi, xlo, whi, wlo, guard, hbuf);

  head_kernel<<<dim3(64, 2, 4), 256, 0, stream>>>(hbuf, conv1_b, wslt, wslb, out,
                                                  fgbuf, (uint4*)hist);
  decode_kernel<<<512, 256, 0, stream>>>(out, fgbuf, roibuf, keys,
                                         out + O4, out, hist, imgh_p, imgw_p);

  select_kernel<<<2, 1024, 0, stream>>>(hist, keys, roibuf, sbox, alive);

  build_mask<<<dim3(96, 4, 2), 256, 0, stream>>>(sbox, maskbuf);
  nms_reduce<<<2, 64, 0, stream>>>(maskbuf, alive, sbox, out);
}